// Round 1
// baseline (25008.603 us; speedup 1.0000x reference)
//
#include <hip/hip_runtime.h>
#include <math.h>

#define TOKENS 8192
#define SEQ    1024
#define BATCH  8
#define DIMM   512
#define NHEADS 8
#define DH     64
#define NDEPTH 6
#define DIN_   524
#define HID    2048
#define NCLS_  1024
#define OUTC   1036   // NCLS + 12

// ---------------------------------------------------------------------------
// Generic fp32 tiled GEMM: C[M,N] = A[M,K] @ B[K,N] (+bias) (+gelu) (+residual)
// BM=BN=64, BK=16, 256 threads, 4x4 micro-tile per thread.
// TRANS: write to d_out with the cls-head transpose mapping.
// ---------------------------------------------------------------------------
template<bool BIAS, bool RES, bool GELU_ACT, bool TRANS>
__global__ __launch_bounds__(256) void gemm_kernel(
    const float* __restrict__ A, int lda,
    const float* __restrict__ B,          // K x N row-major
    const float* __restrict__ bias,
    float* __restrict__ C,
    int M, int N, int K)
{
    __shared__ float As[16 * 68];
    __shared__ float Bs[16 * 68];
    const int tid = threadIdx.x;
    const int tx = tid & 15, ty = tid >> 4;
    const int bm = blockIdx.y * 64;
    const int bn = blockIdx.x * 64;

    float acc[4][4] = {};

    for (int k0 = 0; k0 < K; k0 += 16) {
        #pragma unroll
        for (int i = 0; i < 4; ++i) {
            int e = tid + 256 * i;
            int m = e >> 4, kk = e & 15;
            int kg = k0 + kk;
            float v = 0.f;
            if (kg < K) v = A[(size_t)(bm + m) * lda + kg];
            As[kk * 68 + m] = v;
        }
        #pragma unroll
        for (int i = 0; i < 4; ++i) {
            int e = tid + 256 * i;
            int n = e & 63, kk = e >> 6;
            int kg = k0 + kk, ng = bn + n;
            float v = 0.f;
            if (kg < K && ng < N) v = B[(size_t)kg * N + ng];
            Bs[kk * 68 + n] = v;
        }
        __syncthreads();
        #pragma unroll
        for (int kk = 0; kk < 16; ++kk) {
            float4 a4 = *(const float4*)&As[kk * 68 + ty * 4];
            float4 b4 = *(const float4*)&Bs[kk * 68 + tx * 4];
            float av[4] = {a4.x, a4.y, a4.z, a4.w};
            float bv[4] = {b4.x, b4.y, b4.z, b4.w};
            #pragma unroll
            for (int i = 0; i < 4; ++i)
                #pragma unroll
                for (int j = 0; j < 4; ++j)
                    acc[i][j] = fmaf(av[i], bv[j], acc[i][j]);
        }
        __syncthreads();
    }

    #pragma unroll
    for (int i = 0; i < 4; ++i) {
        int m = bm + ty * 4 + i;
        #pragma unroll
        for (int j = 0; j < 4; ++j) {
            int n = bn + tx * 4 + j;
            if (n >= N) continue;
            float v = acc[i][j];
            if (BIAS) v += bias[n];
            if (GELU_ACT) v = 0.5f * v * (1.0f + erff(v * 0.70710678118654752f));
            if (RES) v += C[(size_t)m * N + n];
            if (TRANS) {
                int b = m >> 10, s = m & 1023;
                C[(size_t)b * (NCLS_ * OUTC) + (size_t)n * OUTC + s] = v;
            } else {
                C[(size_t)m * N + n] = v;
            }
        }
    }
}

// ---------------------------------------------------------------------------
// Embedding + feature concat: x[t, 0:512] = emb_table[idx], x[t, 512:524] = vals
// ---------------------------------------------------------------------------
__global__ __launch_bounds__(256) void embed_kernel(
    const float* __restrict__ saml, const float* __restrict__ emb,
    float* __restrict__ x)
{
    int e = blockIdx.x * 256 + threadIdx.x;
    if (e >= TOKENS * DIN_) return;
    int t = e / DIN_, c = e % DIN_;
    int b = t >> 10, s = t & 1023;
    const float* row = saml + ((size_t)b * 1025 + s) * 13;
    float v;
    if (c < DIMM) {
        int idx = (int)row[0];
        v = emb[(size_t)idx * DIMM + c];
    } else {
        v = row[1 + (c - DIMM)];
    }
    x[(size_t)t * DIN_ + c] = v;
}

// ---------------------------------------------------------------------------
// ScaleNorm: y = x / max(||x||/sqrt(512), 1e-5) * g
// ---------------------------------------------------------------------------
__global__ __launch_bounds__(256) void scalenorm_kernel(
    const float* __restrict__ x, float* __restrict__ y, const float* __restrict__ gptr)
{
    int row = blockIdx.x;
    const float* xr = x + (size_t)row * DIMM;
    int tid = threadIdx.x, lane = tid & 63, wid = tid >> 6;
    float v0 = xr[tid], v1 = xr[tid + 256];
    float ss = v0 * v0 + v1 * v1;
    for (int off = 32; off; off >>= 1) ss += __shfl_down(ss, off, 64);
    __shared__ float red[4];
    if (lane == 0) red[wid] = ss;
    __syncthreads();
    float tot = red[0] + red[1] + red[2] + red[3];
    float n = sqrtf(tot) * 0.04419417382415922f;   // * 512^-0.5
    float f = gptr[0] / fmaxf(n, 1e-5f);
    float* yr = y + (size_t)row * DIMM;
    yr[tid]       = v0 * f;
    yr[tid + 256] = v1 * f;
}

// ---------------------------------------------------------------------------
// LayerNorm
// ---------------------------------------------------------------------------
__global__ __launch_bounds__(256) void ln_kernel(
    const float* __restrict__ x, float* __restrict__ y,
    const float* __restrict__ g, const float* __restrict__ bb)
{
    int row = blockIdx.x;
    const float* xr = x + (size_t)row * DIMM;
    int tid = threadIdx.x, lane = tid & 63, wid = tid >> 6;
    float v0 = xr[tid], v1 = xr[tid + 256];
    __shared__ float red[4];
    float sum = v0 + v1;
    for (int off = 32; off; off >>= 1) sum += __shfl_down(sum, off, 64);
    if (lane == 0) red[wid] = sum;
    __syncthreads();
    float mu = (red[0] + red[1] + red[2] + red[3]) * (1.0f / 512.0f);
    __syncthreads();
    float d0 = v0 - mu, d1 = v1 - mu;
    float vs = d0 * d0 + d1 * d1;
    for (int off = 32; off; off >>= 1) vs += __shfl_down(vs, off, 64);
    if (lane == 0) red[wid] = vs;
    __syncthreads();
    float var = (red[0] + red[1] + red[2] + red[3]) * (1.0f / 512.0f);
    float inv = 1.0f / sqrtf(var + 1e-5f);
    y[(size_t)row * DIMM + tid]       = d0 * inv * g[tid] + bb[tid];
    y[(size_t)row * DIMM + tid + 256] = d1 * inv * g[tid + 256] + bb[tid + 256];
}

// ---------------------------------------------------------------------------
// RoPE in-place on q and k: rotate first 32 dims of each 64-dim head.
// ---------------------------------------------------------------------------
__global__ __launch_bounds__(256) void rope_kernel(float* __restrict__ q, float* __restrict__ k)
{
    int gid = blockIdx.x * 256 + threadIdx.x;   // TOKENS * NHEADS * 16
    int p  = gid & 15;
    int hh = (gid >> 4) & 7;
    int t  = gid >> 7;
    if (t >= TOKENS) return;
    int s = t & 1023;
    float inv = powf(10000.0f, -(float)p * (1.0f / 16.0f));
    float th = (float)s * inv;
    float c = cosf(th), sn = sinf(th);
    size_t base = (size_t)t * DIMM + (size_t)hh * DH;
    float x1 = q[base + p], x2 = q[base + p + 16];
    q[base + p]      = x1 * c - x2 * sn;
    q[base + p + 16] = x2 * c + x1 * sn;
    float y1 = k[base + p], y2 = k[base + p + 16];
    k[base + p]      = y1 * c - y2 * sn;
    k[base + p + 16] = y2 * c + y1 * sn;
}

// ---------------------------------------------------------------------------
// Causal attention, one block per (query i, head h, batch b).
// Full score row in LDS, two-pass softmax. Relpos bias computed inline.
// ---------------------------------------------------------------------------
__global__ __launch_bounds__(256) void attn_kernel(
    const float* __restrict__ q, const float* __restrict__ k, const float* __restrict__ v,
    const float* __restrict__ relpos, float* __restrict__ o)
{
    int i = blockIdx.x;
    int h = blockIdx.y;
    int b = blockIdx.z;
    int tid = threadIdx.x, lane = tid & 63, wid = tid >> 6;
    __shared__ float qs[DH];
    __shared__ float s[SEQ];
    __shared__ float red[8];
    __shared__ float opart[4][DH];

    size_t bh = (size_t)b * SEQ * DIMM + (size_t)h * DH;

    if (tid < DH) qs[tid] = q[bh + (size_t)i * DIMM + tid];
    __syncthreads();

    // scores: one wave per key j
    for (int j = wid; j <= i; j += 4) {
        float p = qs[lane] * k[bh + (size_t)j * DIMM + lane];
        for (int off = 32; off; off >>= 1) p += __shfl_down(p, off, 64);
        if (lane == 0) {
            int n = i - j;
            int bucket;
            if (n < 4) bucket = n;
            else {
                int vl = 4 + (int)(logf((float)n * 0.25f) / logf(8.0f) * 4.0f);
                bucket = vl < 7 ? vl : 7;
            }
            s[j] = p * 0.125f + relpos[bucket * NHEADS + h] * 8.0f;
        }
    }
    __syncthreads();

    // softmax
    float m = -3.402823466e38f;
    for (int j = tid; j <= i; j += 256) m = fmaxf(m, s[j]);
    for (int off = 32; off; off >>= 1) m = fmaxf(m, __shfl_down(m, off, 64));
    if (lane == 0) red[wid] = m;
    __syncthreads();
    m = fmaxf(fmaxf(red[0], red[1]), fmaxf(red[2], red[3]));
    float ssum = 0.f;
    for (int j = tid; j <= i; j += 256) {
        float e = expf(s[j] - m);
        s[j] = e;
        ssum += e;
    }
    for (int off = 32; off; off >>= 1) ssum += __shfl_down(ssum, off, 64);
    if (lane == 0) red[4 + wid] = ssum;
    __syncthreads();
    float denom = red[4] + red[5] + red[6] + red[7];

    // PV
    float accv = 0.f;
    for (int j = wid; j <= i; j += 4)
        accv = fmaf(s[j], v[bh + (size_t)j * DIMM + lane], accv);
    opart[wid][lane] = accv;
    __syncthreads();
    if (wid == 0) {
        float t = opart[0][lane] + opart[1][lane] + opart[2][lane] + opart[3][lane];
        o[bh + (size_t)i * DIMM + lane] = t / denom;
    }
}

// ---------------------------------------------------------------------------
// Tail: copy the 12 pass-through features into output columns 1024..1035
// ---------------------------------------------------------------------------
__global__ __launch_bounds__(256) void tail_kernel(const float* __restrict__ xout, float* __restrict__ out)
{
    int e = blockIdx.x * 256 + threadIdx.x;   // BATCH*SEQ*12
    if (e >= BATCH * SEQ * 12) return;
    int c = e % 12;
    int r = (e / 12) & 1023;
    int b = e / (12 * 1024);
    out[(size_t)b * NCLS_ * OUTC + (size_t)r * OUTC + 1024 + c] =
        xout[((size_t)b * 1024 + r) * DIN_ + 512 + c];
}

// ---------------------------------------------------------------------------
extern "C" void kernel_launch(void* const* d_in, const int* in_sizes, int n_in,
                              void* d_out, int out_size, void* d_ws, size_t ws_size,
                              hipStream_t stream)
{
    const float* saml       = (const float*)d_in[0];
    const float* emb_table  = (const float*)d_in[1];
    const float* proj_in_w  = (const float*)d_in[2];
    const float* proj_in_b  = (const float*)d_in[3];
    const float* g_attn     = (const float*)d_in[4];
    const float* g_ff       = (const float*)d_in[5];
    const float* Wq         = (const float*)d_in[6];
    const float* Wk         = (const float*)d_in[7];
    const float* Wv         = (const float*)d_in[8];
    const float* Wo         = (const float*)d_in[9];
    const float* bo         = (const float*)d_in[10];
    const float* relpos     = (const float*)d_in[11];
    const float* W1         = (const float*)d_in[12];
    const float* b1         = (const float*)d_in[13];
    const float* W2         = (const float*)d_in[14];
    const float* b2         = (const float*)d_in[15];
    const float* ln_g       = (const float*)d_in[16];
    const float* ln_b       = (const float*)d_in[17];
    const float* proj_out_w = (const float*)d_in[18];
    const float* proj_out_b = (const float*)d_in[19];
    const float* cls_w      = (const float*)d_in[20];
    const float* cls_b      = (const float*)d_in[21];
    float* out = (float*)d_out;

    float* ws = (float*)d_ws;
    const size_t SZ = (size_t)TOKENS * DIMM;        // 4,194,304
    float* h     = ws;
    float* bufA  = h     + SZ;
    float* bufB  = bufA  + SZ;
    float* bufK  = bufB  + SZ;
    float* bufV  = bufK  + SZ;
    float* bufFF = bufV  + SZ;                      // TOKENS*HID
    float* bufX  = bufFF + (size_t)TOKENS * HID;    // TOKENS*DIN_

    dim3 blk(256);

    // x = concat(emb[idx], vals)
    embed_kernel<<<(TOKENS * DIN_ + 255) / 256, blk, 0, stream>>>(saml, emb_table, bufX);
    // h = x @ proj_in_w + proj_in_b
    gemm_kernel<true, false, false, false><<<dim3(DIMM / 64, TOKENS / 64), blk, 0, stream>>>(
        bufX, DIN_, proj_in_w, proj_in_b, h, TOKENS, DIMM, DIN_);

    for (int l = 0; l < NDEPTH; ++l) {
        const float* wq = Wq + (size_t)l * DIMM * DIMM;
        const float* wk = Wk + (size_t)l * DIMM * DIMM;
        const float* wv = Wv + (size_t)l * DIMM * DIMM;
        const float* wo = Wo + (size_t)l * DIMM * DIMM;
        const float* w1 = W1 + (size_t)l * DIMM * HID;
        const float* w2 = W2 + (size_t)l * HID * DIMM;

        scalenorm_kernel<<<TOKENS, blk, 0, stream>>>(h, bufA, g_attn + l);
        gemm_kernel<false, false, false, false><<<dim3(DIMM / 64, TOKENS / 64), blk, 0, stream>>>(
            bufA, DIMM, wq, nullptr, bufB, TOKENS, DIMM, DIMM);
        gemm_kernel<false, false, false, false><<<dim3(DIMM / 64, TOKENS / 64), blk, 0, stream>>>(
            bufA, DIMM, wk, nullptr, bufK, TOKENS, DIMM, DIMM);
        gemm_kernel<false, false, false, false><<<dim3(DIMM / 64, TOKENS / 64), blk, 0, stream>>>(
            bufA, DIMM, wv, nullptr, bufV, TOKENS, DIMM, DIMM);
        rope_kernel<<<(TOKENS * NHEADS * 16) / 256, blk, 0, stream>>>(bufB, bufK);
        attn_kernel<<<dim3(SEQ, NHEADS, BATCH), blk, 0, stream>>>(bufB, bufK, bufV, relpos, bufA);
        // h = h + o @ Wo + bo
        gemm_kernel<true, true, false, false><<<dim3(DIMM / 64, TOKENS / 64), blk, 0, stream>>>(
            bufA, DIMM, wo, bo + (size_t)l * DIMM, h, TOKENS, DIMM, DIMM);
        scalenorm_kernel<<<TOKENS, blk, 0, stream>>>(h, bufB, g_ff + l);
        // ff1 = gelu(hn @ W1 + b1)
        gemm_kernel<true, false, true, false><<<dim3(HID / 64, TOKENS / 64), blk, 0, stream>>>(
            bufB, DIMM, w1, b1 + (size_t)l * HID, bufFF, TOKENS, HID, DIMM);
        // h = h + ff1 @ W2 + b2
        gemm_kernel<true, true, false, false><<<dim3(DIMM / 64, TOKENS / 64), blk, 0, stream>>>(
            bufFF, HID, w2, b2 + (size_t)l * DIMM, h, TOKENS, DIMM, HID);
    }

    ln_kernel<<<TOKENS, blk, 0, stream>>>(h, bufA, ln_g, ln_b);
    // outproj = hn @ proj_out_w + proj_out_b   (8192 x 524)
    gemm_kernel<true, false, false, false><<<dim3((DIN_ + 63) / 64, TOKENS / 64), blk, 0, stream>>>(
        bufA, DIMM, proj_out_w, proj_out_b, bufX, TOKENS, DIN_, DIMM);
    // logits (transposed into d_out): out[b, n, s] = outproj[b,s,:512] @ cls_w + cls_b
    gemm_kernel<true, false, false, true><<<dim3(NCLS_ / 64, TOKENS / 64), blk, 0, stream>>>(
        bufX, DIN_, cls_w, cls_b, out, TOKENS, NCLS_, DIMM);
    tail_kernel<<<(BATCH * SEQ * 12 + 255) / 256, blk, 0, stream>>>(bufX, out);
}

// Round 2
// 8394.090 us; speedup vs baseline: 2.9793x; 2.9793x over previous
//
#include <hip/hip_runtime.h>
#include <math.h>

#define TOKENS 8192
#define SEQ    1024
#define BATCH  8
#define DIMM   512
#define NHEADS 8
#define DH     64
#define NDEPTH 6
#define DIN_   524
#define HID    2048
#define NCLS_  1024
#define OUTC   1036   // NCLS + 12

// ---------------------------------------------------------------------------
// Generic fp32 tiled GEMM: C[M,N] = A[M,K] @ B[K,N] (+bias) (+gelu) (+residual)
// BM=BN=64, BK=16, 256 threads, 4x4 micro-tile per thread.
// TRANS: write to d_out with the cls-head transpose mapping.
// ---------------------------------------------------------------------------
template<bool BIAS, bool RES, bool GELU_ACT, bool TRANS>
__global__ __launch_bounds__(256) void gemm_kernel(
    const float* __restrict__ A, int lda,
    const float* __restrict__ B,          // K x N row-major
    const float* __restrict__ bias,
    float* __restrict__ C,
    int M, int N, int K)
{
    __shared__ float As[16 * 68];
    __shared__ float Bs[16 * 68];
    const int tid = threadIdx.x;
    const int tx = tid & 15, ty = tid >> 4;
    const int bm = blockIdx.y * 64;
    const int bn = blockIdx.x * 64;

    float acc[4][4] = {};

    for (int k0 = 0; k0 < K; k0 += 16) {
        #pragma unroll
        for (int i = 0; i < 4; ++i) {
            int e = tid + 256 * i;
            int m = e >> 4, kk = e & 15;
            int kg = k0 + kk;
            float v = 0.f;
            if (kg < K) v = A[(size_t)(bm + m) * lda + kg];
            As[kk * 68 + m] = v;
        }
        #pragma unroll
        for (int i = 0; i < 4; ++i) {
            int e = tid + 256 * i;
            int n = e & 63, kk = e >> 6;
            int kg = k0 + kk, ng = bn + n;
            float v = 0.f;
            if (kg < K && ng < N) v = B[(size_t)kg * N + ng];
            Bs[kk * 68 + n] = v;
        }
        __syncthreads();
        #pragma unroll
        for (int kk = 0; kk < 16; ++kk) {
            float4 a4 = *(const float4*)&As[kk * 68 + ty * 4];
            float4 b4 = *(const float4*)&Bs[kk * 68 + tx * 4];
            float av[4] = {a4.x, a4.y, a4.z, a4.w};
            float bv[4] = {b4.x, b4.y, b4.z, b4.w};
            #pragma unroll
            for (int i = 0; i < 4; ++i)
                #pragma unroll
                for (int j = 0; j < 4; ++j)
                    acc[i][j] = fmaf(av[i], bv[j], acc[i][j]);
        }
        __syncthreads();
    }

    #pragma unroll
    for (int i = 0; i < 4; ++i) {
        int m = bm + ty * 4 + i;
        #pragma unroll
        for (int j = 0; j < 4; ++j) {
            int n = bn + tx * 4 + j;
            if (n >= N) continue;
            float v = acc[i][j];
            if (BIAS) v += bias[n];
            if (GELU_ACT) v = 0.5f * v * (1.0f + erff(v * 0.70710678118654752f));
            if (RES) v += C[(size_t)m * N + n];
            if (TRANS) {
                int b = m >> 10, s = m & 1023;
                C[(size_t)b * (NCLS_ * OUTC) + (size_t)n * OUTC + s] = v;
            } else {
                C[(size_t)m * N + n] = v;
            }
        }
    }
}

// ---------------------------------------------------------------------------
// Embedding + feature concat
// ---------------------------------------------------------------------------
__global__ __launch_bounds__(256) void embed_kernel(
    const float* __restrict__ saml, const float* __restrict__ emb,
    float* __restrict__ x)
{
    int e = blockIdx.x * 256 + threadIdx.x;
    if (e >= TOKENS * DIN_) return;
    int t = e / DIN_, c = e % DIN_;
    int b = t >> 10, s = t & 1023;
    const float* row = saml + ((size_t)b * 1025 + s) * 13;
    float v;
    if (c < DIMM) {
        int idx = (int)row[0];
        v = emb[(size_t)idx * DIMM + c];
    } else {
        v = row[1 + (c - DIMM)];
    }
    x[(size_t)t * DIN_ + c] = v;
}

// ---------------------------------------------------------------------------
// ScaleNorm
// ---------------------------------------------------------------------------
__global__ __launch_bounds__(256) void scalenorm_kernel(
    const float* __restrict__ x, float* __restrict__ y, const float* __restrict__ gptr)
{
    int row = blockIdx.x;
    const float* xr = x + (size_t)row * DIMM;
    int tid = threadIdx.x, lane = tid & 63, wid = tid >> 6;
    float v0 = xr[tid], v1 = xr[tid + 256];
    float ss = v0 * v0 + v1 * v1;
    for (int off = 32; off; off >>= 1) ss += __shfl_down(ss, off, 64);
    __shared__ float red[4];
    if (lane == 0) red[wid] = ss;
    __syncthreads();
    float tot = red[0] + red[1] + red[2] + red[3];
    float n = sqrtf(tot) * 0.04419417382415922f;
    float f = gptr[0] / fmaxf(n, 1e-5f);
    float* yr = y + (size_t)row * DIMM;
    yr[tid]       = v0 * f;
    yr[tid + 256] = v1 * f;
}

// ---------------------------------------------------------------------------
// LayerNorm
// ---------------------------------------------------------------------------
__global__ __launch_bounds__(256) void ln_kernel(
    const float* __restrict__ x, float* __restrict__ y,
    const float* __restrict__ g, const float* __restrict__ bb)
{
    int row = blockIdx.x;
    const float* xr = x + (size_t)row * DIMM;
    int tid = threadIdx.x, lane = tid & 63, wid = tid >> 6;
    float v0 = xr[tid], v1 = xr[tid + 256];
    __shared__ float red[4];
    float sum = v0 + v1;
    for (int off = 32; off; off >>= 1) sum += __shfl_down(sum, off, 64);
    if (lane == 0) red[wid] = sum;
    __syncthreads();
    float mu = (red[0] + red[1] + red[2] + red[3]) * (1.0f / 512.0f);
    __syncthreads();
    float d0 = v0 - mu, d1 = v1 - mu;
    float vs = d0 * d0 + d1 * d1;
    for (int off = 32; off; off >>= 1) vs += __shfl_down(vs, off, 64);
    if (lane == 0) red[wid] = vs;
    __syncthreads();
    float var = (red[0] + red[1] + red[2] + red[3]) * (1.0f / 512.0f);
    float inv = 1.0f / sqrtf(var + 1e-5f);
    y[(size_t)row * DIMM + tid]       = d0 * inv * g[tid] + bb[tid];
    y[(size_t)row * DIMM + tid + 256] = d1 * inv * g[tid + 256] + bb[tid + 256];
}

// ---------------------------------------------------------------------------
// RoPE in-place on q and k
// ---------------------------------------------------------------------------
__global__ __launch_bounds__(256) void rope_kernel(float* __restrict__ q, float* __restrict__ k)
{
    int gid = blockIdx.x * 256 + threadIdx.x;
    int p  = gid & 15;
    int hh = (gid >> 4) & 7;
    int t  = gid >> 7;
    if (t >= TOKENS) return;
    int s = t & 1023;
    float inv = powf(10000.0f, -(float)p * (1.0f / 16.0f));
    float th = (float)s * inv;
    float c = cosf(th), sn = sinf(th);
    size_t base = (size_t)t * DIMM + (size_t)hh * DH;
    float x1 = q[base + p], x2 = q[base + p + 16];
    q[base + p]      = x1 * c - x2 * sn;
    q[base + p + 16] = x2 * c + x1 * sn;
    float y1 = k[base + p], y2 = k[base + p + 16];
    k[base + p]      = y1 * c - y2 * sn;
    k[base + p + 16] = y2 * c + y1 * sn;
}

// ---------------------------------------------------------------------------
// Flash-style tiled causal attention (fp32).
// Grid: (SEQ/64, NHEADS, BATCH). 256 threads, 4x4 micro-tile per thread.
// Q/K staged transposed in LDS ([d][i]); V natural; P goes through LDS
// transposed ([j][i]) for the PV GEMM. Online softmax, 16-lane xor reduce.
// ---------------------------------------------------------------------------
__global__ __launch_bounds__(256) void fattn_kernel(
    const float* __restrict__ q, const float* __restrict__ k, const float* __restrict__ v,
    const float* __restrict__ relpos, float* __restrict__ o)
{
    const int qt = blockIdx.x;
    const int h = blockIdx.y;
    const int b = blockIdx.z;
    const int tid = threadIdx.x;
    const int tx = tid & 15, ty = tid >> 4;

    __shared__ float Qs[64 * 68];   // [d][i]
    __shared__ float Ks[64 * 68];   // [d][j]
    __shared__ float Vs[64 * 68];   // [j][d]
    __shared__ float Ps[64 * 68];   // [j][i]
    __shared__ float bias_d[SEQ];

    const size_t bh = (size_t)b * SEQ * DIMM + (size_t)h * DH;
    const int i0 = qt * 64;

    // per-head relpos bias table over delta = i - j (>=0 in causal region)
    for (int n = tid; n < SEQ; n += 256) {
        int bucket;
        if (n < 4) bucket = n;
        else {
            int vl = 4 + (int)(logf((float)n * 0.25f) * (4.0f / logf(8.0f)));
            bucket = vl < 7 ? vl : 7;
        }
        bias_d[n] = relpos[bucket * NHEADS + h] * 8.0f;
    }

    // load Q tile transposed
    #pragma unroll
    for (int it = 0; it < 4; ++it) {
        int e = tid + 256 * it;           // 0..1023
        int row = e >> 4;
        int d4 = (e & 15) * 4;
        float4 qv = *(const float4*)&q[bh + (size_t)(i0 + row) * DIMM + d4];
        Qs[(d4 + 0) * 68 + row] = qv.x;
        Qs[(d4 + 1) * 68 + row] = qv.y;
        Qs[(d4 + 2) * 68 + row] = qv.z;
        Qs[(d4 + 3) * 68 + row] = qv.w;
    }
    __syncthreads();

    float o_acc[4][4] = {};
    float m_r[4], l_r[4];
    #pragma unroll
    for (int i = 0; i < 4; ++i) { m_r[i] = -3.0e38f; l_r[i] = 0.f; }

    for (int jt = 0; jt <= qt; ++jt) {
        const int j0 = jt * 64;
        #pragma unroll
        for (int it = 0; it < 4; ++it) {
            int e = tid + 256 * it;
            int row = e >> 4;
            int d4 = (e & 15) * 4;
            float4 kv = *(const float4*)&k[bh + (size_t)(j0 + row) * DIMM + d4];
            Ks[(d4 + 0) * 68 + row] = kv.x;
            Ks[(d4 + 1) * 68 + row] = kv.y;
            Ks[(d4 + 2) * 68 + row] = kv.z;
            Ks[(d4 + 3) * 68 + row] = kv.w;
            float4 vv = *(const float4*)&v[bh + (size_t)(j0 + row) * DIMM + d4];
            *(float4*)&Vs[row * 68 + d4] = vv;
        }
        __syncthreads();

        // S = Q K^T  (64x64, 4x4 per thread)
        float s[4][4] = {};
        #pragma unroll 8
        for (int d = 0; d < 64; ++d) {
            float4 a4 = *(const float4*)&Qs[d * 68 + ty * 4];
            float4 b4 = *(const float4*)&Ks[d * 68 + tx * 4];
            float av[4] = {a4.x, a4.y, a4.z, a4.w};
            float bv[4] = {b4.x, b4.y, b4.z, b4.w};
            #pragma unroll
            for (int i = 0; i < 4; ++i)
                #pragma unroll
                for (int j = 0; j < 4; ++j)
                    s[i][j] = fmaf(av[i], bv[j], s[i][j]);
        }

        // scale + bias + causal mask
        const bool diag = (jt == qt);
        #pragma unroll
        for (int i = 0; i < 4; ++i) {
            int gi = i0 + ty * 4 + i;
            #pragma unroll
            for (int j = 0; j < 4; ++j) {
                int gj = j0 + tx * 4 + j;
                if (diag && gj > gi) s[i][j] = -1.0e30f;
                else s[i][j] = s[i][j] * 0.125f + bias_d[gi - gj];
            }
        }

        // online softmax: row reductions across the 16 lanes sharing a row
        float rm[4];
        #pragma unroll
        for (int i = 0; i < 4; ++i)
            rm[i] = fmaxf(fmaxf(s[i][0], s[i][1]), fmaxf(s[i][2], s[i][3]));
        #pragma unroll
        for (int off = 1; off < 16; off <<= 1)
            #pragma unroll
            for (int i = 0; i < 4; ++i)
                rm[i] = fmaxf(rm[i], __shfl_xor(rm[i], off, 64));

        float pscale[4];
        #pragma unroll
        for (int i = 0; i < 4; ++i) {
            float mn = fmaxf(m_r[i], rm[i]);
            pscale[i] = __expf(m_r[i] - mn);
            m_r[i] = mn;
        }
        float rs[4] = {};
        #pragma unroll
        for (int i = 0; i < 4; ++i)
            #pragma unroll
            for (int j = 0; j < 4; ++j) {
                s[i][j] = __expf(s[i][j] - m_r[i]);
                rs[i] += s[i][j];
            }
        #pragma unroll
        for (int off = 1; off < 16; off <<= 1)
            #pragma unroll
            for (int i = 0; i < 4; ++i)
                rs[i] += __shfl_xor(rs[i], off, 64);
        #pragma unroll
        for (int i = 0; i < 4; ++i) {
            l_r[i] = l_r[i] * pscale[i] + rs[i];
            #pragma unroll
            for (int j = 0; j < 4; ++j) o_acc[i][j] *= pscale[i];
        }

        // write P transposed to LDS: Ps[j][i]
        #pragma unroll
        for (int j = 0; j < 4; ++j) {
            float4 pv = make_float4(s[0][j], s[1][j], s[2][j], s[3][j]);
            *(float4*)&Ps[(tx * 4 + j) * 68 + ty * 4] = pv;
        }
        __syncthreads();

        // O += P @ V
        #pragma unroll 8
        for (int j = 0; j < 64; ++j) {
            float4 a4 = *(const float4*)&Ps[j * 68 + ty * 4];
            float4 b4 = *(const float4*)&Vs[j * 68 + tx * 4];
            float av[4] = {a4.x, a4.y, a4.z, a4.w};
            float bv[4] = {b4.x, b4.y, b4.z, b4.w};
            #pragma unroll
            for (int i = 0; i < 4; ++i)
                #pragma unroll
                for (int jj = 0; jj < 4; ++jj)
                    o_acc[i][jj] = fmaf(av[i], bv[jj], o_acc[i][jj]);
        }
        __syncthreads();
    }

    #pragma unroll
    for (int i = 0; i < 4; ++i) {
        float inv = 1.0f / l_r[i];
        int gi = i0 + ty * 4 + i;
        #pragma unroll
        for (int j = 0; j < 4; ++j)
            o[bh + (size_t)gi * DIMM + tx * 4 + j] = o_acc[i][j] * inv;
    }
}

// ---------------------------------------------------------------------------
// Tail: copy the 12 pass-through features into output columns 1024..1035
// ---------------------------------------------------------------------------
__global__ __launch_bounds__(256) void tail_kernel(const float* __restrict__ xout, float* __restrict__ out)
{
    int e = blockIdx.x * 256 + threadIdx.x;
    if (e >= BATCH * SEQ * 12) return;
    int c = e % 12;
    int r = (e / 12) & 1023;
    int b = e / (12 * 1024);
    out[(size_t)b * NCLS_ * OUTC + (size_t)r * OUTC + 1024 + c] =
        xout[((size_t)b * 1024 + r) * DIN_ + 512 + c];
}

// ---------------------------------------------------------------------------
extern "C" void kernel_launch(void* const* d_in, const int* in_sizes, int n_in,
                              void* d_out, int out_size, void* d_ws, size_t ws_size,
                              hipStream_t stream)
{
    const float* saml       = (const float*)d_in[0];
    const float* emb_table  = (const float*)d_in[1];
    const float* proj_in_w  = (const float*)d_in[2];
    const float* proj_in_b  = (const float*)d_in[3];
    const float* g_attn     = (const float*)d_in[4];
    const float* g_ff       = (const float*)d_in[5];
    const float* Wq         = (const float*)d_in[6];
    const float* Wk         = (const float*)d_in[7];
    const float* Wv         = (const float*)d_in[8];
    const float* Wo         = (const float*)d_in[9];
    const float* bo         = (const float*)d_in[10];
    const float* relpos     = (const float*)d_in[11];
    const float* W1         = (const float*)d_in[12];
    const float* b1         = (const float*)d_in[13];
    const float* W2         = (const float*)d_in[14];
    const float* b2         = (const float*)d_in[15];
    const float* ln_g       = (const float*)d_in[16];
    const float* ln_b       = (const float*)d_in[17];
    const float* proj_out_w = (const float*)d_in[18];
    const float* proj_out_b = (const float*)d_in[19];
    const float* cls_w      = (const float*)d_in[20];
    const float* cls_b      = (const float*)d_in[21];
    float* out = (float*)d_out;

    float* ws = (float*)d_ws;
    const size_t SZ = (size_t)TOKENS * DIMM;
    float* h     = ws;
    float* bufA  = h     + SZ;
    float* bufB  = bufA  + SZ;
    float* bufK  = bufB  + SZ;
    float* bufV  = bufK  + SZ;
    float* bufFF = bufV  + SZ;
    float* bufX  = bufFF + (size_t)TOKENS * HID;

    dim3 blk(256);

    embed_kernel<<<(TOKENS * DIN_ + 255) / 256, blk, 0, stream>>>(saml, emb_table, bufX);
    gemm_kernel<true, false, false, false><<<dim3(DIMM / 64, TOKENS / 64), blk, 0, stream>>>(
        bufX, DIN_, proj_in_w, proj_in_b, h, TOKENS, DIMM, DIN_);

    for (int l = 0; l < NDEPTH; ++l) {
        const float* wq = Wq + (size_t)l * DIMM * DIMM;
        const float* wk = Wk + (size_t)l * DIMM * DIMM;
        const float* wv = Wv + (size_t)l * DIMM * DIMM;
        const float* wo = Wo + (size_t)l * DIMM * DIMM;
        const float* w1 = W1 + (size_t)l * DIMM * HID;
        const float* w2 = W2 + (size_t)l * HID * DIMM;

        scalenorm_kernel<<<TOKENS, blk, 0, stream>>>(h, bufA, g_attn + l);
        gemm_kernel<false, false, false, false><<<dim3(DIMM / 64, TOKENS / 64), blk, 0, stream>>>(
            bufA, DIMM, wq, nullptr, bufB, TOKENS, DIMM, DIMM);
        gemm_kernel<false, false, false, false><<<dim3(DIMM / 64, TOKENS / 64), blk, 0, stream>>>(
            bufA, DIMM, wk, nullptr, bufK, TOKENS, DIMM, DIMM);
        gemm_kernel<false, false, false, false><<<dim3(DIMM / 64, TOKENS / 64), blk, 0, stream>>>(
            bufA, DIMM, wv, nullptr, bufV, TOKENS, DIMM, DIMM);
        rope_kernel<<<(TOKENS * NHEADS * 16) / 256, blk, 0, stream>>>(bufB, bufK);
        fattn_kernel<<<dim3(SEQ / 64, NHEADS, BATCH), blk, 0, stream>>>(bufB, bufK, bufV, relpos, bufA);
        gemm_kernel<true, true, false, false><<<dim3(DIMM / 64, TOKENS / 64), blk, 0, stream>>>(
            bufA, DIMM, wo, bo + (size_t)l * DIMM, h, TOKENS, DIMM, DIMM);
        scalenorm_kernel<<<TOKENS, blk, 0, stream>>>(h, bufB, g_ff + l);
        gemm_kernel<true, false, true, false><<<dim3(HID / 64, TOKENS / 64), blk, 0, stream>>>(
            bufB, DIMM, w1, b1 + (size_t)l * HID, bufFF, TOKENS, HID, DIMM);
        gemm_kernel<true, true, false, false><<<dim3(DIMM / 64, TOKENS / 64), blk, 0, stream>>>(
            bufFF, HID, w2, b2 + (size_t)l * DIMM, h, TOKENS, DIMM, HID);
    }

    ln_kernel<<<TOKENS, blk, 0, stream>>>(h, bufA, ln_g, ln_b);
    gemm_kernel<true, false, false, false><<<dim3((DIN_ + 63) / 64, TOKENS / 64), blk, 0, stream>>>(
        bufA, DIMM, proj_out_w, proj_out_b, bufX, TOKENS, DIN_, DIMM);
    gemm_kernel<true, false, false, true><<<dim3(NCLS_ / 64, TOKENS / 64), blk, 0, stream>>>(
        bufX, DIN_, cls_w, cls_b, out, TOKENS, NCLS_, DIMM);
    tail_kernel<<<(BATCH * SEQ * 12 + 255) / 256, blk, 0, stream>>>(bufX, out);
}

// Round 3
// 3155.162 us; speedup vs baseline: 7.9263x; 2.6604x over previous
//
#include <hip/hip_runtime.h>
#include <math.h>

#define TOKENS 8192
#define SEQ    1024
#define BATCH  8
#define DIMM   512
#define NHEADS 8
#define DH     64
#define NDEPTH 6
#define HID    2048
#define NCLS_  1024
#define OUTC   1036   // NCLS + 12
#define KPIN   544    // DIN=524 padded to multiple of 32
#define NPOUT  640    // proj-out N=524 padded to multiple of 128

typedef __attribute__((ext_vector_type(8))) short bf16x8;
typedef __attribute__((ext_vector_type(4))) float f32x4;

__device__ __forceinline__ float b2f(unsigned short u) {
    return __uint_as_float(((unsigned)u) << 16);
}
__device__ __forceinline__ unsigned short f2b(float f) {
    unsigned u = __float_as_uint(f);
    u += 0x7FFFu + ((u >> 16) & 1u);
    return (unsigned short)(u >> 16);
}
__device__ __forceinline__ void gl_lds16(const void* g, void* l) {
    __builtin_amdgcn_global_load_lds((const __attribute__((address_space(1))) void*)g,
                                     (__attribute__((address_space(3))) void*)l, 16, 0, 0);
}

// ---------------------------------------------------------------------------
// bf16 MFMA GEMM (m97 structure): C = A[M,Kp] @ Bt[N,Kp]^T, 128x128 tile,
// BK=32, 4 waves (2x2), 4x4 16x16x32 fragments per wave.
// MODE: 0 bias->fp32 | 1 plain->bf16 | 2 bias+residual->fp32 (Cf += )
//       3 bias+gelu->bf16 | 4 proj_out (bf16 clsin + passthrough scatter)
//       5 cls transpose scatter -> fp32 | 6 RoPE -> bf16 (Q/K)
// ---------------------------------------------------------------------------
template<int MODE>
__global__ __launch_bounds__(256) void gemm_bf16(
    const unsigned short* __restrict__ A, int Kp,
    const unsigned short* __restrict__ Bt,
    const float* __restrict__ bias,
    float* __restrict__ Cf,
    unsigned short* __restrict__ Cb,
    int N)
{
    __shared__ unsigned short As[128 * 32];
    __shared__ unsigned short Bs[128 * 32];
    const int tid = threadIdx.x;
    const int lane = tid & 63, wid = tid >> 6;
    const int wr = wid >> 1, wc = wid & 1;
    const int m0 = blockIdx.y * 128, n0 = blockIdx.x * 128;

    f32x4 acc[4][4] = {};

    const int srow = lane >> 2;          // row within 16-row chunk
    const int skk  = (lane & 3) * 8;     // k offset within 32

    for (int k0 = 0; k0 < Kp; k0 += 32) {
        #pragma unroll
        for (int c = 0; c < 2; ++c) {
            int chunk = wid * 2 + c;
            int row = chunk * 16 + srow;
            gl_lds16(A  + (size_t)(m0 + row) * Kp + k0 + skk, As + chunk * 512);
            gl_lds16(Bt + (size_t)(n0 + row) * Kp + k0 + skk, Bs + chunk * 512);
        }
        __syncthreads();
        bf16x8 a[4], b[4];
        const int fr = lane & 15, fo = (lane >> 4) * 8;
        #pragma unroll
        for (int mi = 0; mi < 4; ++mi)
            a[mi] = *(const bf16x8*)(As + (wr * 64 + mi * 16 + fr) * 32 + fo);
        #pragma unroll
        for (int ni = 0; ni < 4; ++ni)
            b[ni] = *(const bf16x8*)(Bs + (wc * 64 + ni * 16 + fr) * 32 + fo);
        #pragma unroll
        for (int mi = 0; mi < 4; ++mi)
            #pragma unroll
            for (int ni = 0; ni < 4; ++ni)
                acc[mi][ni] = __builtin_amdgcn_mfma_f32_16x16x32_bf16(a[mi], b[ni], acc[mi][ni], 0, 0, 0);
        __syncthreads();
    }

    const int col16 = lane & 15;
    const int rbase = (lane >> 4) * 4;

    if (MODE == 6) {
        // RoPE epilogue: wave's 64 cols = one head; pair (d, d+16) = (ni=0, ni=1)
        const float invp = powf(10000.0f, -(float)col16 * (1.0f / 16.0f));
        #pragma unroll
        for (int mi = 0; mi < 4; ++mi) {
            #pragma unroll
            for (int r = 0; r < 4; ++r) {
                int mm = m0 + wr * 64 + mi * 16 + rbase + r;
                int s = mm & (SEQ - 1);
                float sn, cs;
                sincosf((float)s * invp, &sn, &cs);
                float v0 = acc[mi][0][r], v1 = acc[mi][1][r];
                size_t base = (size_t)mm * N + n0 + wc * 64 + col16;
                Cb[base]      = f2b(v0 * cs - v1 * sn);
                Cb[base + 16] = f2b(v1 * cs + v0 * sn);
                Cb[base + 32] = f2b(acc[mi][2][r]);
                Cb[base + 48] = f2b(acc[mi][3][r]);
            }
        }
        return;
    }

    #pragma unroll
    for (int mi = 0; mi < 4; ++mi) {
        #pragma unroll
        for (int ni = 0; ni < 4; ++ni) {
            int nn = n0 + wc * 64 + ni * 16 + col16;
            if (MODE == 4 && nn >= 524) continue;
            float bv = (MODE == 1) ? 0.f : bias[nn];
            #pragma unroll
            for (int r = 0; r < 4; ++r) {
                int mm = m0 + wr * 64 + mi * 16 + rbase + r;
                float vv = acc[mi][ni][r] + bv;
                if (MODE == 3) vv = 0.5f * vv * (1.0f + erff(vv * 0.70710678118654752f));
                if (MODE == 0) Cf[(size_t)mm * N + nn] = vv;
                if (MODE == 1 || MODE == 3) Cb[(size_t)mm * N + nn] = f2b(vv);
                if (MODE == 2) Cf[(size_t)mm * N + nn] += vv;
                if (MODE == 4) {
                    if (nn < 512) Cb[(size_t)mm * 512 + nn] = f2b(vv);
                    else {
                        int bb = mm >> 10, ss = mm & 1023;
                        Cf[(size_t)bb * (SEQ * OUTC) + (size_t)ss * OUTC + 512 + nn] = vv;
                    }
                }
                if (MODE == 5) {
                    int bb = mm >> 10, ss = mm & 1023;
                    Cf[(size_t)bb * (NCLS_ * OUTC) + (size_t)nn * OUTC + ss] = vv;
                }
            }
        }
    }
}

// ---------------------------------------------------------------------------
// Weight convert: fp32 src[K][N] -> bf16 dst[Np][Kp] (transposed, zero-padded)
// ---------------------------------------------------------------------------
__global__ __launch_bounds__(256) void convw_kernel(
    const float* __restrict__ src, unsigned short* __restrict__ dst,
    int K, int N, int Kp, long sstride, long dstride)
{
    src += (size_t)blockIdx.z * sstride;
    dst += (size_t)blockIdx.z * dstride;
    __shared__ float t[32][33];
    int k0 = blockIdx.y * 32, n0 = blockIdx.x * 32;
    int tx = threadIdx.x & 31, ty = threadIdx.x >> 5;
    #pragma unroll
    for (int i = 0; i < 4; ++i) {
        int k = k0 + ty + i * 8, n = n0 + tx;
        t[ty + i * 8][tx] = (k < K && n < N) ? src[(size_t)k * N + n] : 0.f;
    }
    __syncthreads();
    #pragma unroll
    for (int i = 0; i < 4; ++i) {
        int n = n0 + ty + i * 8;
        dst[(size_t)n * Kp + k0 + tx] = f2b(t[tx][ty + i * 8]);
    }
}

// ---------------------------------------------------------------------------
// Embedding + feature concat -> bf16 [TOKENS][KPIN], zero pad cols 524..544
// ---------------------------------------------------------------------------
__global__ __launch_bounds__(256) void embed_kernel(
    const float* __restrict__ saml, const float* __restrict__ emb,
    unsigned short* __restrict__ x)
{
    int e = blockIdx.x * 256 + threadIdx.x;
    if (e >= TOKENS * KPIN) return;
    int t = e / KPIN, c = e % KPIN;
    int b = t >> 10, s = t & 1023;
    const float* row = saml + ((size_t)b * 1025 + s) * 13;
    float v;
    if (c < DIMM) v = emb[(size_t)((int)row[0]) * DIMM + c];
    else if (c < 524) v = row[1 + (c - DIMM)];
    else v = 0.f;
    x[(size_t)t * KPIN + c] = f2b(v);
}

// ---------------------------------------------------------------------------
// ScaleNorm: fp32 in -> bf16 out
// ---------------------------------------------------------------------------
__global__ __launch_bounds__(256) void scalenorm_kernel(
    const float* __restrict__ x, unsigned short* __restrict__ y,
    const float* __restrict__ gptr)
{
    int row = blockIdx.x;
    const float* xr = x + (size_t)row * DIMM;
    int tid = threadIdx.x, lane = tid & 63, wid = tid >> 6;
    float v0 = xr[tid], v1 = xr[tid + 256];
    float ss = v0 * v0 + v1 * v1;
    for (int off = 32; off; off >>= 1) ss += __shfl_down(ss, off, 64);
    __shared__ float red[4];
    if (lane == 0) red[wid] = ss;
    __syncthreads();
    float tot = red[0] + red[1] + red[2] + red[3];
    float n = sqrtf(tot) * 0.04419417382415922f;
    float f = gptr[0] / fmaxf(n, 1e-5f);
    y[(size_t)row * DIMM + tid]       = f2b(v0 * f);
    y[(size_t)row * DIMM + tid + 256] = f2b(v1 * f);
}

// ---------------------------------------------------------------------------
// LayerNorm: fp32 in -> bf16 out
// ---------------------------------------------------------------------------
__global__ __launch_bounds__(256) void ln_kernel(
    const float* __restrict__ x, unsigned short* __restrict__ y,
    const float* __restrict__ g, const float* __restrict__ bb)
{
    int row = blockIdx.x;
    const float* xr = x + (size_t)row * DIMM;
    int tid = threadIdx.x, lane = tid & 63, wid = tid >> 6;
    float v0 = xr[tid], v1 = xr[tid + 256];
    __shared__ float red[4];
    float sum = v0 + v1;
    for (int off = 32; off; off >>= 1) sum += __shfl_down(sum, off, 64);
    if (lane == 0) red[wid] = sum;
    __syncthreads();
    float mu = (red[0] + red[1] + red[2] + red[3]) * (1.0f / 512.0f);
    __syncthreads();
    float d0 = v0 - mu, d1 = v1 - mu;
    float vs = d0 * d0 + d1 * d1;
    for (int off = 32; off; off >>= 1) vs += __shfl_down(vs, off, 64);
    if (lane == 0) red[wid] = vs;
    __syncthreads();
    float var = (red[0] + red[1] + red[2] + red[3]) * (1.0f / 512.0f);
    float inv = 1.0f / sqrtf(var + 1e-5f);
    y[(size_t)row * DIMM + tid]       = f2b(d0 * inv * g[tid] + bb[tid]);
    y[(size_t)row * DIMM + tid + 256] = f2b(d1 * inv * g[tid + 256] + bb[tid + 256]);
}

// ---------------------------------------------------------------------------
// Flash-style tiled causal attention, fp32 compute, bf16 in/out.
// ---------------------------------------------------------------------------
__global__ __launch_bounds__(256) void fattn_kernel(
    const unsigned short* __restrict__ q, const unsigned short* __restrict__ k,
    const unsigned short* __restrict__ v,
    const float* __restrict__ relpos, unsigned short* __restrict__ o)
{
    const int qt = blockIdx.x;
    const int h = blockIdx.y;
    const int b = blockIdx.z;
    const int tid = threadIdx.x;
    const int tx = tid & 15, ty = tid >> 4;

    __shared__ float Qs[64 * 68];   // [d][i]
    __shared__ float Ks[64 * 68];   // [d][j]
    __shared__ float Vs[64 * 68];   // [j][d]
    __shared__ float Ps[64 * 68];   // [j][i]
    __shared__ float bias_d[SEQ];

    const size_t bh = (size_t)b * SEQ * DIMM + (size_t)h * DH;
    const int i0 = qt * 64;

    for (int n = tid; n < SEQ; n += 256) {
        int bucket;
        if (n < 4) bucket = n;
        else {
            int vl = 4 + (int)(logf((float)n * 0.25f) * (4.0f / logf(8.0f)));
            bucket = vl < 7 ? vl : 7;
        }
        bias_d[n] = relpos[bucket * NHEADS + h] * 8.0f;
    }

    #pragma unroll
    for (int it = 0; it < 2; ++it) {
        int e = tid + 256 * it;           // 0..511
        int row = e >> 3;
        int d8 = (e & 7) * 8;
        uint4 pk = *(const uint4*)(q + bh + (size_t)(i0 + row) * DIMM + d8);
        const unsigned short* s8 = (const unsigned short*)&pk;
        #pragma unroll
        for (int j = 0; j < 8; ++j) Qs[(d8 + j) * 68 + row] = b2f(s8[j]);
    }
    __syncthreads();

    float o_acc[4][4] = {};
    float m_r[4], l_r[4];
    #pragma unroll
    for (int i = 0; i < 4; ++i) { m_r[i] = -3.0e38f; l_r[i] = 0.f; }

    for (int jt = 0; jt <= qt; ++jt) {
        const int j0 = jt * 64;
        #pragma unroll
        for (int it = 0; it < 2; ++it) {
            int e = tid + 256 * it;
            int row = e >> 3;
            int d8 = (e & 7) * 8;
            uint4 pk = *(const uint4*)(k + bh + (size_t)(j0 + row) * DIMM + d8);
            const unsigned short* s8 = (const unsigned short*)&pk;
            #pragma unroll
            for (int j = 0; j < 8; ++j) Ks[(d8 + j) * 68 + row] = b2f(s8[j]);
            uint4 pv = *(const uint4*)(v + bh + (size_t)(j0 + row) * DIMM + d8);
            const unsigned short* t8 = (const unsigned short*)&pv;
            #pragma unroll
            for (int j = 0; j < 8; ++j) Vs[row * 68 + d8 + j] = b2f(t8[j]);
        }
        __syncthreads();

        float s[4][4] = {};
        #pragma unroll 8
        for (int d = 0; d < 64; ++d) {
            float4 a4 = *(const float4*)&Qs[d * 68 + ty * 4];
            float4 b4 = *(const float4*)&Ks[d * 68 + tx * 4];
            float av[4] = {a4.x, a4.y, a4.z, a4.w};
            float bv[4] = {b4.x, b4.y, b4.z, b4.w};
            #pragma unroll
            for (int i = 0; i < 4; ++i)
                #pragma unroll
                for (int j = 0; j < 4; ++j)
                    s[i][j] = fmaf(av[i], bv[j], s[i][j]);
        }

        const bool diag = (jt == qt);
        #pragma unroll
        for (int i = 0; i < 4; ++i) {
            int gi = i0 + ty * 4 + i;
            #pragma unroll
            for (int j = 0; j < 4; ++j) {
                int gj = j0 + tx * 4 + j;
                if (diag && gj > gi) s[i][j] = -1.0e30f;
                else s[i][j] = s[i][j] * 0.125f + bias_d[gi - gj];
            }
        }

        float rm[4];
        #pragma unroll
        for (int i = 0; i < 4; ++i)
            rm[i] = fmaxf(fmaxf(s[i][0], s[i][1]), fmaxf(s[i][2], s[i][3]));
        #pragma unroll
        for (int off = 1; off < 16; off <<= 1)
            #pragma unroll
            for (int i = 0; i < 4; ++i)
                rm[i] = fmaxf(rm[i], __shfl_xor(rm[i], off, 64));

        float pscale[4];
        #pragma unroll
        for (int i = 0; i < 4; ++i) {
            float mn = fmaxf(m_r[i], rm[i]);
            pscale[i] = __expf(m_r[i] - mn);
            m_r[i] = mn;
        }
        float rs[4] = {};
        #pragma unroll
        for (int i = 0; i < 4; ++i)
            #pragma unroll
            for (int j = 0; j < 4; ++j) {
                s[i][j] = __expf(s[i][j] - m_r[i]);
                rs[i] += s[i][j];
            }
        #pragma unroll
        for (int off = 1; off < 16; off <<= 1)
            #pragma unroll
            for (int i = 0; i < 4; ++i)
                rs[i] += __shfl_xor(rs[i], off, 64);
        #pragma unroll
        for (int i = 0; i < 4; ++i) {
            l_r[i] = l_r[i] * pscale[i] + rs[i];
            #pragma unroll
            for (int j = 0; j < 4; ++j) o_acc[i][j] *= pscale[i];
        }

        #pragma unroll
        for (int j = 0; j < 4; ++j) {
            float4 pv = make_float4(s[0][j], s[1][j], s[2][j], s[3][j]);
            *(float4*)&Ps[(tx * 4 + j) * 68 + ty * 4] = pv;
        }
        __syncthreads();

        #pragma unroll 8
        for (int j = 0; j < 64; ++j) {
            float4 a4 = *(const float4*)&Ps[j * 68 + ty * 4];
            float4 b4 = *(const float4*)&Vs[j * 68 + tx * 4];
            float av[4] = {a4.x, a4.y, a4.z, a4.w};
            float bv[4] = {b4.x, b4.y, b4.z, b4.w};
            #pragma unroll
            for (int i = 0; i < 4; ++i)
                #pragma unroll
                for (int jj = 0; jj < 4; ++jj)
                    o_acc[i][jj] = fmaf(av[i], bv[jj], o_acc[i][jj]);
        }
        __syncthreads();
    }

    #pragma unroll
    for (int i = 0; i < 4; ++i) {
        float inv = 1.0f / l_r[i];
        int gi = i0 + ty * 4 + i;
        #pragma unroll
        for (int j = 0; j < 4; ++j)
            o[bh + (size_t)gi * DIMM + tx * 4 + j] = f2b(o_acc[i][j] * inv);
    }
}

// ---------------------------------------------------------------------------
extern "C" void kernel_launch(void* const* d_in, const int* in_sizes, int n_in,
                              void* d_out, int out_size, void* d_ws, size_t ws_size,
                              hipStream_t stream)
{
    const float* saml       = (const float*)d_in[0];
    const float* emb_table  = (const float*)d_in[1];
    const float* proj_in_w  = (const float*)d_in[2];
    const float* proj_in_b  = (const float*)d_in[3];
    const float* g_attn     = (const float*)d_in[4];
    const float* g_ff       = (const float*)d_in[5];
    const float* Wq         = (const float*)d_in[6];
    const float* Wk         = (const float*)d_in[7];
    const float* Wv         = (const float*)d_in[8];
    const float* Wo         = (const float*)d_in[9];
    const float* bo         = (const float*)d_in[10];
    const float* relpos     = (const float*)d_in[11];
    const float* W1         = (const float*)d_in[12];
    const float* b1         = (const float*)d_in[13];
    const float* W2         = (const float*)d_in[14];
    const float* b2         = (const float*)d_in[15];
    const float* ln_g       = (const float*)d_in[16];
    const float* ln_b       = (const float*)d_in[17];
    const float* proj_out_w = (const float*)d_in[18];
    const float* proj_out_b = (const float*)d_in[19];
    const float* cls_w      = (const float*)d_in[20];
    const float* cls_b      = (const float*)d_in[21];
    float* out = (float*)d_out;

    char* wsp = (char*)d_ws;
    size_t woff = 0;
    auto carve = [&](size_t bytes) -> char* {
        char* p = wsp + woff;
        woff += (bytes + 255) & ~(size_t)255;
        return p;
    };
    typedef unsigned short u16;
    float* h  = (float*)carve((size_t)TOKENS * DIMM * 4);
    u16* qb   = (u16*)carve((size_t)TOKENS * DIMM * 2);
    u16* kb   = (u16*)carve((size_t)TOKENS * DIMM * 2);
    u16* vb   = (u16*)carve((size_t)TOKENS * DIMM * 2);
    u16* ab   = (u16*)carve((size_t)TOKENS * DIMM * 2);   // norm outputs
    u16* ob   = (u16*)carve((size_t)TOKENS * DIMM * 2);   // attention out
    u16* ff   = (u16*)carve((size_t)TOKENS * HID * 2);
    u16* ci   = (u16*)carve((size_t)TOKENS * DIMM * 2);   // cls input
    u16* xb   = (u16*)carve((size_t)TOKENS * KPIN * 2);
    u16* wqT  = (u16*)carve((size_t)NDEPTH * DIMM * DIMM * 2);
    u16* wkT  = (u16*)carve((size_t)NDEPTH * DIMM * DIMM * 2);
    u16* wvT  = (u16*)carve((size_t)NDEPTH * DIMM * DIMM * 2);
    u16* woT  = (u16*)carve((size_t)NDEPTH * DIMM * DIMM * 2);
    u16* w1T  = (u16*)carve((size_t)NDEPTH * HID * DIMM * 2);
    u16* w2T  = (u16*)carve((size_t)NDEPTH * DIMM * HID * 2);
    u16* pinT = (u16*)carve((size_t)DIMM * KPIN * 2);
    u16* poutT= (u16*)carve((size_t)NPOUT * DIMM * 2);
    u16* clsT = (u16*)carve((size_t)NCLS_ * DIMM * 2);

    dim3 blk(256);

    // weight conversion (fp32 [K][N] -> bf16 [N][Kp] transposed)
    convw_kernel<<<dim3(16, 16, 6), blk, 0, stream>>>(Wq, wqT, 512, 512, 512, 512*512, 512*512);
    convw_kernel<<<dim3(16, 16, 6), blk, 0, stream>>>(Wk, wkT, 512, 512, 512, 512*512, 512*512);
    convw_kernel<<<dim3(16, 16, 6), blk, 0, stream>>>(Wv, wvT, 512, 512, 512, 512*512, 512*512);
    convw_kernel<<<dim3(16, 16, 6), blk, 0, stream>>>(Wo, woT, 512, 512, 512, 512*512, 512*512);
    convw_kernel<<<dim3(64, 16, 6), blk, 0, stream>>>(W1, w1T, 512, 2048, 512, 512*2048, 2048*512);
    convw_kernel<<<dim3(16, 64, 6), blk, 0, stream>>>(W2, w2T, 2048, 512, 2048, 2048*512, 512*2048);
    convw_kernel<<<dim3(16, 17, 1), blk, 0, stream>>>(proj_in_w, pinT, 524, 512, KPIN, 0, 0);
    convw_kernel<<<dim3(20, 16, 1), blk, 0, stream>>>(proj_out_w, poutT, 512, 524, 512, 0, 0);
    convw_kernel<<<dim3(32, 16, 1), blk, 0, stream>>>(cls_w, clsT, 512, 1024, 512, 0, 0);

    embed_kernel<<<(TOKENS * KPIN + 255) / 256, blk, 0, stream>>>(saml, emb_table, xb);
    gemm_bf16<0><<<dim3(4, 64), blk, 0, stream>>>(xb, KPIN, pinT, proj_in_b, h, nullptr, DIMM);

    for (int l = 0; l < NDEPTH; ++l) {
        const u16* wq = wqT + (size_t)l * DIMM * DIMM;
        const u16* wk = wkT + (size_t)l * DIMM * DIMM;
        const u16* wv = wvT + (size_t)l * DIMM * DIMM;
        const u16* wo = woT + (size_t)l * DIMM * DIMM;
        const u16* w1 = w1T + (size_t)l * HID * DIMM;
        const u16* w2 = w2T + (size_t)l * DIMM * HID;

        scalenorm_kernel<<<TOKENS, blk, 0, stream>>>(h, ab, g_attn + l);
        gemm_bf16<6><<<dim3(4, 64), blk, 0, stream>>>(ab, DIMM, wq, nullptr, nullptr, qb, DIMM);
        gemm_bf16<6><<<dim3(4, 64), blk, 0, stream>>>(ab, DIMM, wk, nullptr, nullptr, kb, DIMM);
        gemm_bf16<1><<<dim3(4, 64), blk, 0, stream>>>(ab, DIMM, wv, nullptr, nullptr, vb, DIMM);
        fattn_kernel<<<dim3(SEQ / 64, NHEADS, BATCH), blk, 0, stream>>>(qb, kb, vb, relpos, ob);
        gemm_bf16<2><<<dim3(4, 64), blk, 0, stream>>>(ob, DIMM, wo, bo + (size_t)l * DIMM, h, nullptr, DIMM);
        scalenorm_kernel<<<TOKENS, blk, 0, stream>>>(h, ab, g_ff + l);
        gemm_bf16<3><<<dim3(16, 64), blk, 0, stream>>>(ab, DIMM, w1, b1 + (size_t)l * HID, nullptr, ff, HID);
        gemm_bf16<2><<<dim3(4, 64), blk, 0, stream>>>(ff, HID, w2, b2 + (size_t)l * DIMM, h, nullptr, DIMM);
    }

    ln_kernel<<<TOKENS, blk, 0, stream>>>(h, ab, ln_g, ln_b);
    // proj_out: bf16 clsin (cols<512) + fp32 passthrough scatter (cols 512..524)
    gemm_bf16<4><<<dim3(5, 64), blk, 0, stream>>>(ab, DIMM, poutT, proj_out_b, out, ci, 524);
    // cls head, transposed scatter into d_out
    gemm_bf16<5><<<dim3(8, 64), blk, 0, stream>>>(ci, DIMM, clsT, cls_b, out, nullptr, NCLS_);
}

// Round 4
// 1908.553 us; speedup vs baseline: 13.1034x; 1.6532x over previous
//
#include <hip/hip_runtime.h>
#include <math.h>

#define TOKENS 8192
#define SEQ    1024
#define BATCH  8
#define DIMM   512
#define NHEADS 8
#define DH     64
#define NDEPTH 6
#define HID    2048
#define NCLS_  1024
#define OUTC   1036   // NCLS + 12
#define KPIN   544    // DIN=524 padded to multiple of 32
#define LDK    72     // LDS row stride (u16) for attention tiles

typedef __attribute__((ext_vector_type(8))) short bf16x8;
typedef __attribute__((ext_vector_type(4))) float f32x4;

__device__ __forceinline__ float b2f(unsigned short u) {
    return __uint_as_float(((unsigned)u) << 16);
}
__device__ __forceinline__ unsigned short f2b(float f) {
    unsigned u = __float_as_uint(f);
    u += 0x7FFFu + ((u >> 16) & 1u);
    return (unsigned short)(u >> 16);
}
__device__ __forceinline__ void gl_lds16(const void* g, void* l) {
    __builtin_amdgcn_global_load_lds((const __attribute__((address_space(1))) void*)g,
                                     (__attribute__((address_space(3))) void*)l, 16, 0, 0);
}

// ---------------------------------------------------------------------------
// bf16 MFMA GEMM (m97 structure): C = A[M,Kp] @ Bt[N,Kp]^T, 128x128 tile,
// BK=32, 4 waves (2x2), 4x4 16x16x32 fragments per wave.
// MODE: 0 bias->fp32 | 1 plain->bf16 | 2 bias+residual->fp32 (Cf += )
//       3 bias+gelu->bf16 | 4 proj_out (bf16 clsin + passthrough scatter)
//       5 cls transpose scatter -> fp32 | 7 fused QKV epilogue (RoPE on Q,K)
// ---------------------------------------------------------------------------
template<int MODE>
__global__ __launch_bounds__(256) void gemm_bf16(
    const unsigned short* __restrict__ A, int Kp,
    const unsigned short* __restrict__ Bt,
    const float* __restrict__ bias,
    float* __restrict__ Cf,
    unsigned short* __restrict__ Cb,
    int N)
{
    __shared__ unsigned short As[128 * 32];
    __shared__ unsigned short Bs[128 * 32];
    const int tid = threadIdx.x;
    const int lane = tid & 63, wid = tid >> 6;
    const int wr = wid >> 1, wc = wid & 1;
    const int m0 = blockIdx.y * 128, n0 = blockIdx.x * 128;

    f32x4 acc[4][4] = {};

    const int srow = lane >> 2;          // row within 16-row chunk
    const int skk  = (lane & 3) * 8;     // k offset within 32

    for (int k0 = 0; k0 < Kp; k0 += 32) {
        #pragma unroll
        for (int c = 0; c < 2; ++c) {
            int chunk = wid * 2 + c;
            int row = chunk * 16 + srow;
            gl_lds16(A  + (size_t)(m0 + row) * Kp + k0 + skk, As + chunk * 512);
            gl_lds16(Bt + (size_t)(n0 + row) * Kp + k0 + skk, Bs + chunk * 512);
        }
        __syncthreads();
        bf16x8 a[4], b[4];
        const int fr = lane & 15, fo = (lane >> 4) * 8;
        #pragma unroll
        for (int mi = 0; mi < 4; ++mi)
            a[mi] = *(const bf16x8*)(As + (wr * 64 + mi * 16 + fr) * 32 + fo);
        #pragma unroll
        for (int ni = 0; ni < 4; ++ni)
            b[ni] = *(const bf16x8*)(Bs + (wc * 64 + ni * 16 + fr) * 32 + fo);
        #pragma unroll
        for (int mi = 0; mi < 4; ++mi)
            #pragma unroll
            for (int ni = 0; ni < 4; ++ni)
                acc[mi][ni] = __builtin_amdgcn_mfma_f32_16x16x32_bf16(a[mi], b[ni], acc[mi][ni], 0, 0, 0);
        __syncthreads();
    }

    const int col16 = lane & 15;
    const int rbase = (lane >> 4) * 4;

    if (MODE == 7) {
        // fused QKV: wave's 64-col block lies in one of Q(0)/K(1)/V(2)
        const int nbase = n0 + wc * 64;
        const int which = nbase >> 9;
        const int col0 = nbase & 511;
        unsigned short* dst = Cb + (size_t)which * ((size_t)TOKENS * DIMM);
        if (which < 2) {
            const float invp = powf(10000.0f, -(float)col16 * (1.0f / 16.0f));
            #pragma unroll
            for (int mi = 0; mi < 4; ++mi) {
                #pragma unroll
                for (int r = 0; r < 4; ++r) {
                    int mm = m0 + wr * 64 + mi * 16 + rbase + r;
                    int s = mm & (SEQ - 1);
                    float sn, cs;
                    sincosf((float)s * invp, &sn, &cs);
                    float v0 = acc[mi][0][r], v1 = acc[mi][1][r];
                    size_t base = (size_t)mm * DIMM + col0 + col16;
                    dst[base]      = f2b(v0 * cs - v1 * sn);
                    dst[base + 16] = f2b(v1 * cs + v0 * sn);
                    dst[base + 32] = f2b(acc[mi][2][r]);
                    dst[base + 48] = f2b(acc[mi][3][r]);
                }
            }
        } else {
            #pragma unroll
            for (int mi = 0; mi < 4; ++mi)
                #pragma unroll
                for (int ni = 0; ni < 4; ++ni)
                    #pragma unroll
                    for (int r = 0; r < 4; ++r) {
                        int mm = m0 + wr * 64 + mi * 16 + rbase + r;
                        dst[(size_t)mm * DIMM + col0 + ni * 16 + col16] = f2b(acc[mi][ni][r]);
                    }
        }
        return;
    }

    #pragma unroll
    for (int mi = 0; mi < 4; ++mi) {
        #pragma unroll
        for (int ni = 0; ni < 4; ++ni) {
            int nn = n0 + wc * 64 + ni * 16 + col16;
            if (MODE == 4 && nn >= 524) continue;
            float bv = (MODE == 1) ? 0.f : bias[nn];
            #pragma unroll
            for (int r = 0; r < 4; ++r) {
                int mm = m0 + wr * 64 + mi * 16 + rbase + r;
                float vv = acc[mi][ni][r] + bv;
                if (MODE == 3) vv = 0.5f * vv * (1.0f + erff(vv * 0.70710678118654752f));
                if (MODE == 0) Cf[(size_t)mm * N + nn] = vv;
                if (MODE == 1 || MODE == 3) Cb[(size_t)mm * N + nn] = f2b(vv);
                if (MODE == 2) Cf[(size_t)mm * N + nn] += vv;
                if (MODE == 4) {
                    if (nn < 512) Cb[(size_t)mm * 512 + nn] = f2b(vv);
                    else {
                        int bb = mm >> 10, ss = mm & 1023;
                        Cf[(size_t)bb * (SEQ * OUTC) + (size_t)ss * OUTC + 512 + nn] = vv;
                    }
                }
                if (MODE == 5) {
                    int bb = mm >> 10, ss = mm & 1023;
                    Cf[(size_t)bb * (NCLS_ * OUTC) + (size_t)nn * OUTC + ss] = vv;
                }
            }
        }
    }
}

// ---------------------------------------------------------------------------
// Weight convert: fp32 src[K][N] -> bf16 dst[Np][Kp] (transposed, zero-padded)
// ---------------------------------------------------------------------------
__global__ __launch_bounds__(256) void convw_kernel(
    const float* __restrict__ src, unsigned short* __restrict__ dst,
    int K, int N, int Kp, long sstride, long dstride)
{
    src += (size_t)blockIdx.z * sstride;
    dst += (size_t)blockIdx.z * dstride;
    __shared__ float t[32][33];
    int k0 = blockIdx.y * 32, n0 = blockIdx.x * 32;
    int tx = threadIdx.x & 31, ty = threadIdx.x >> 5;
    #pragma unroll
    for (int i = 0; i < 4; ++i) {
        int k = k0 + ty + i * 8, n = n0 + tx;
        t[ty + i * 8][tx] = (k < K && n < N) ? src[(size_t)k * N + n] : 0.f;
    }
    __syncthreads();
    #pragma unroll
    for (int i = 0; i < 4; ++i) {
        int n = n0 + ty + i * 8;
        dst[(size_t)n * Kp + k0 + tx] = f2b(t[tx][ty + i * 8]);
    }
}

// ---------------------------------------------------------------------------
// Embedding + feature concat -> bf16 [TOKENS][KPIN]
// ---------------------------------------------------------------------------
__global__ __launch_bounds__(256) void embed_kernel(
    const float* __restrict__ saml, const float* __restrict__ emb,
    unsigned short* __restrict__ x)
{
    int e = blockIdx.x * 256 + threadIdx.x;
    if (e >= TOKENS * KPIN) return;
    int t = e / KPIN, c = e % KPIN;
    int b = t >> 10, s = t & 1023;
    const float* row = saml + ((size_t)b * 1025 + s) * 13;
    float v;
    if (c < DIMM) v = emb[(size_t)((int)row[0]) * DIMM + c];
    else if (c < 524) v = row[1 + (c - DIMM)];
    else v = 0.f;
    x[(size_t)t * KPIN + c] = f2b(v);
}

// ---------------------------------------------------------------------------
// ScaleNorm: fp32 in -> bf16 out
// ---------------------------------------------------------------------------
__global__ __launch_bounds__(256) void scalenorm_kernel(
    const float* __restrict__ x, unsigned short* __restrict__ y,
    const float* __restrict__ gptr)
{
    int row = blockIdx.x;
    const float* xr = x + (size_t)row * DIMM;
    int tid = threadIdx.x, lane = tid & 63, wid = tid >> 6;
    float v0 = xr[tid], v1 = xr[tid + 256];
    float ss = v0 * v0 + v1 * v1;
    for (int off = 32; off; off >>= 1) ss += __shfl_down(ss, off, 64);
    __shared__ float red[4];
    if (lane == 0) red[wid] = ss;
    __syncthreads();
    float tot = red[0] + red[1] + red[2] + red[3];
    float n = sqrtf(tot) * 0.04419417382415922f;
    float f = gptr[0] / fmaxf(n, 1e-5f);
    y[(size_t)row * DIMM + tid]       = f2b(v0 * f);
    y[(size_t)row * DIMM + tid + 256] = f2b(v1 * f);
}

// ---------------------------------------------------------------------------
// LayerNorm: fp32 in -> bf16 out
// ---------------------------------------------------------------------------
__global__ __launch_bounds__(256) void ln_kernel(
    const float* __restrict__ x, unsigned short* __restrict__ y,
    const float* __restrict__ g, const float* __restrict__ bb)
{
    int row = blockIdx.x;
    const float* xr = x + (size_t)row * DIMM;
    int tid = threadIdx.x, lane = tid & 63, wid = tid >> 6;
    float v0 = xr[tid], v1 = xr[tid + 256];
    __shared__ float red[4];
    float sum = v0 + v1;
    for (int off = 32; off; off >>= 1) sum += __shfl_down(sum, off, 64);
    if (lane == 0) red[wid] = sum;
    __syncthreads();
    float mu = (red[0] + red[1] + red[2] + red[3]) * (1.0f / 512.0f);
    __syncthreads();
    float d0 = v0 - mu, d1 = v1 - mu;
    float vs = d0 * d0 + d1 * d1;
    for (int off = 32; off; off >>= 1) vs += __shfl_down(vs, off, 64);
    if (lane == 0) red[wid] = vs;
    __syncthreads();
    float var = (red[0] + red[1] + red[2] + red[3]) * (1.0f / 512.0f);
    float inv = 1.0f / sqrtf(var + 1e-5f);
    y[(size_t)row * DIMM + tid]       = f2b(d0 * inv * g[tid] + bb[tid]);
    y[(size_t)row * DIMM + tid + 256] = f2b(d1 * inv * g[tid + 256] + bb[tid + 256]);
}

// ---------------------------------------------------------------------------
// MFMA flash attention. Grid (SEQ/64, NHEADS, BATCH), 256 threads = 4 waves.
// Each wave owns a 16-query-row strip. Q fragments in registers; K [j][d],
// V^T [d][j], P [i][j] staged in LDS with row stride LDK=72 (bank-rotating).
// ---------------------------------------------------------------------------
__global__ __launch_bounds__(256) void fattn_kernel(
    const unsigned short* __restrict__ q, const unsigned short* __restrict__ k,
    const unsigned short* __restrict__ v,
    const float* __restrict__ relpos, unsigned short* __restrict__ o)
{
    const int qt = blockIdx.x;
    const int h = blockIdx.y;
    const int b = blockIdx.z;
    const int tid = threadIdx.x;
    const int lane = tid & 63, wid = tid >> 6;
    const int l15 = lane & 15, hi = lane >> 4;

    __shared__ __align__(16) unsigned short Ks[64 * LDK];
    __shared__ __align__(16) unsigned short Vt[64 * LDK];
    __shared__ __align__(16) unsigned short Ps[64 * LDK];
    __shared__ float bias_d[SEQ];

    const size_t bh = (size_t)b * SEQ * DIMM + (size_t)h * DH;
    const int i0 = qt * 64;

    for (int n = tid; n < SEQ; n += 256) {
        int bucket;
        if (n < 4) bucket = n;
        else {
            int vl = 4 + (int)(logf((float)n * 0.25f) * (4.0f / logf(8.0f)));
            bucket = vl < 7 ? vl : 7;
        }
        bias_d[n] = relpos[bucket * NHEADS + h] * 8.0f;
    }

    // Q A-fragments in registers: row = i0 + wid*16 + l15, k-chunks d
    bf16x8 qf[2];
    {
        const unsigned short* qrow = q + bh + (size_t)(i0 + wid * 16 + l15) * DIMM;
        qf[0] = *(const bf16x8*)(qrow + hi * 8);
        qf[1] = *(const bf16x8*)(qrow + 32 + hi * 8);
    }

    f32x4 o_acc[4] = {};
    float m_r[4], l_r[4];
    #pragma unroll
    for (int r = 0; r < 4; ++r) { m_r[r] = -3.0e38f; l_r[r] = 0.f; }

    for (int jt = 0; jt <= qt; ++jt) {
        const int j0 = jt * 64;
        __syncthreads();   // prev iter done reading Ks/Vt/Ps
        #pragma unroll
        for (int it = 0; it < 2; ++it) {
            int e = tid + 256 * it;       // 0..511
            int j = e >> 3;
            int d8 = (e & 7) * 8;
            uint4 kv = *(const uint4*)(k + bh + (size_t)(j0 + j) * DIMM + d8);
            *(uint4*)&Ks[j * LDK + d8] = kv;
            uint4 vv = *(const uint4*)(v + bh + (size_t)(j0 + j) * DIMM + d8);
            const unsigned short* p8 = (const unsigned short*)&vv;
            #pragma unroll
            for (int jj = 0; jj < 8; ++jj)
                Vt[(d8 + jj) * LDK + j] = p8[jj];
        }
        __syncthreads();

        // S = Q K^T : 4 col-fragments x 2 k-steps
        f32x4 sacc[4] = {};
        #pragma unroll
        for (int nj = 0; nj < 4; ++nj) {
            #pragma unroll
            for (int kk = 0; kk < 2; ++kk) {
                bf16x8 kf = *(const bf16x8*)(Ks + (nj * 16 + l15) * LDK + kk * 32 + hi * 8);
                sacc[nj] = __builtin_amdgcn_mfma_f32_16x16x32_bf16(qf[kk], kf, sacc[nj], 0, 0, 0);
            }
        }

        // epilogue: scale + bias + causal mask
        float s4[4][4];
        const bool diag = (jt == qt);
        const int gi_base = i0 + wid * 16 + hi * 4;
        #pragma unroll
        for (int nj = 0; nj < 4; ++nj) {
            int gj = j0 + nj * 16 + l15;
            #pragma unroll
            for (int r = 0; r < 4; ++r) {
                int gi = gi_base + r;
                if (diag && gj > gi) s4[nj][r] = -1.0e30f;
                else s4[nj][r] = sacc[nj][r] * 0.125f + bias_d[gi - gj];
            }
        }

        // online softmax (rows = 16-lane groups)
        float rm[4];
        #pragma unroll
        for (int r = 0; r < 4; ++r)
            rm[r] = fmaxf(fmaxf(s4[0][r], s4[1][r]), fmaxf(s4[2][r], s4[3][r]));
        #pragma unroll
        for (int off = 1; off < 16; off <<= 1)
            #pragma unroll
            for (int r = 0; r < 4; ++r)
                rm[r] = fmaxf(rm[r], __shfl_xor(rm[r], off, 64));

        float pscale[4];
        #pragma unroll
        for (int r = 0; r < 4; ++r) {
            float mn = fmaxf(m_r[r], rm[r]);
            pscale[r] = __expf(m_r[r] - mn);
            m_r[r] = mn;
        }
        float rs[4] = {};
        #pragma unroll
        for (int nj = 0; nj < 4; ++nj)
            #pragma unroll
            for (int r = 0; r < 4; ++r) {
                float e = __expf(s4[nj][r] - m_r[r]);
                rs[r] += e;
                Ps[(wid * 16 + hi * 4 + r) * LDK + nj * 16 + l15] = f2b(e);
            }
        #pragma unroll
        for (int off = 1; off < 16; off <<= 1)
            #pragma unroll
            for (int r = 0; r < 4; ++r)
                rs[r] += __shfl_xor(rs[r], off, 64);
        #pragma unroll
        for (int r = 0; r < 4; ++r)
            l_r[r] = l_r[r] * pscale[r] + rs[r];
        #pragma unroll
        for (int ni = 0; ni < 4; ++ni)
            #pragma unroll
            for (int r = 0; r < 4; ++r)
                o_acc[ni][r] *= pscale[r];
        __syncthreads();   // Ps visible to whole wave... (wave-local but cross-lane via LDS)

        // O += P V : A = P strip rows, B = Vt rows (= d)
        #pragma unroll
        for (int kk = 0; kk < 2; ++kk) {
            bf16x8 pf = *(const bf16x8*)(Ps + (wid * 16 + l15) * LDK + kk * 32 + hi * 8);
            #pragma unroll
            for (int ni = 0; ni < 4; ++ni) {
                bf16x8 vf = *(const bf16x8*)(Vt + (ni * 16 + l15) * LDK + kk * 32 + hi * 8);
                o_acc[ni] = __builtin_amdgcn_mfma_f32_16x16x32_bf16(pf, vf, o_acc[ni], 0, 0, 0);
            }
        }
    }

    #pragma unroll
    for (int r = 0; r < 4; ++r) {
        float inv = 1.0f / l_r[r];
        int gi = i0 + wid * 16 + hi * 4 + r;
        #pragma unroll
        for (int ni = 0; ni < 4; ++ni)
            o[bh + (size_t)gi * DIMM + ni * 16 + l15] = f2b(o_acc[ni][r] * inv);
    }
}

// ---------------------------------------------------------------------------
extern "C" void kernel_launch(void* const* d_in, const int* in_sizes, int n_in,
                              void* d_out, int out_size, void* d_ws, size_t ws_size,
                              hipStream_t stream)
{
    const float* saml       = (const float*)d_in[0];
    const float* emb_table  = (const float*)d_in[1];
    const float* proj_in_w  = (const float*)d_in[2];
    const float* proj_in_b  = (const float*)d_in[3];
    const float* g_attn     = (const float*)d_in[4];
    const float* g_ff       = (const float*)d_in[5];
    const float* Wq         = (const float*)d_in[6];
    const float* Wk         = (const float*)d_in[7];
    const float* Wv         = (const float*)d_in[8];
    const float* Wo         = (const float*)d_in[9];
    const float* bo         = (const float*)d_in[10];
    const float* relpos     = (const float*)d_in[11];
    const float* W1         = (const float*)d_in[12];
    const float* b1         = (const float*)d_in[13];
    const float* W2         = (const float*)d_in[14];
    const float* b2         = (const float*)d_in[15];
    const float* ln_g       = (const float*)d_in[16];
    const float* ln_b       = (const float*)d_in[17];
    const float* proj_out_w = (const float*)d_in[18];
    const float* proj_out_b = (const float*)d_in[19];
    const float* cls_w      = (const float*)d_in[20];
    const float* cls_b      = (const float*)d_in[21];
    float* out = (float*)d_out;

    char* wsp = (char*)d_ws;
    size_t woff = 0;
    auto carve = [&](size_t bytes) -> char* {
        char* p = wsp + woff;
        woff += (bytes + 255) & ~(size_t)255;
        return p;
    };
    typedef unsigned short u16;
    float* h  = (float*)carve((size_t)TOKENS * DIMM * 4);
    u16* qb   = (u16*)carve((size_t)TOKENS * DIMM * 2);   // qb,kb,vb contiguous!
    u16* kb   = (u16*)carve((size_t)TOKENS * DIMM * 2);
    u16* vb   = (u16*)carve((size_t)TOKENS * DIMM * 2);
    u16* ab   = (u16*)carve((size_t)TOKENS * DIMM * 2);   // norm outputs
    u16* ob   = (u16*)carve((size_t)TOKENS * DIMM * 2);   // attention out
    u16* ff   = (u16*)carve((size_t)TOKENS * HID * 2);
    u16* ci   = (u16*)carve((size_t)TOKENS * DIMM * 2);   // cls input
    u16* xb   = (u16*)carve((size_t)TOKENS * KPIN * 2);
    u16* qkvT = (u16*)carve((size_t)NDEPTH * 1536 * DIMM * 2);
    u16* woT  = (u16*)carve((size_t)NDEPTH * DIMM * DIMM * 2);
    u16* w1T  = (u16*)carve((size_t)NDEPTH * HID * DIMM * 2);
    u16* w2T  = (u16*)carve((size_t)NDEPTH * DIMM * HID * 2);
    u16* pinT = (u16*)carve((size_t)DIMM * KPIN * 2);
    u16* poutT= (u16*)carve((size_t)640 * DIMM * 2);
    u16* clsT = (u16*)carve((size_t)NCLS_ * DIMM * 2);

    dim3 blk(256);

    convw_kernel<<<dim3(16, 16, 6), blk, 0, stream>>>(Wq, qkvT,             512, 512, 512, 512*512, 1536*512);
    convw_kernel<<<dim3(16, 16, 6), blk, 0, stream>>>(Wk, qkvT + 512*512,   512, 512, 512, 512*512, 1536*512);
    convw_kernel<<<dim3(16, 16, 6), blk, 0, stream>>>(Wv, qkvT + 1024*512,  512, 512, 512, 512*512, 1536*512);
    convw_kernel<<<dim3(16, 16, 6), blk, 0, stream>>>(Wo, woT, 512, 512, 512, 512*512, 512*512);
    convw_kernel<<<dim3(64, 16, 6), blk, 0, stream>>>(W1, w1T, 512, 2048, 512, 512*2048, 2048*512);
    convw_kernel<<<dim3(16, 64, 6), blk, 0, stream>>>(W2, w2T, 2048, 512, 2048, 2048*512, 512*2048);
    convw_kernel<<<dim3(16, 17, 1), blk, 0, stream>>>(proj_in_w, pinT, 524, 512, KPIN, 0, 0);
    convw_kernel<<<dim3(20, 16, 1), blk, 0, stream>>>(proj_out_w, poutT, 512, 524, 512, 0, 0);
    convw_kernel<<<dim3(32, 16, 1), blk, 0, stream>>>(cls_w, clsT, 512, 1024, 512, 0, 0);

    embed_kernel<<<(TOKENS * KPIN + 255) / 256, blk, 0, stream>>>(saml, emb_table, xb);
    gemm_bf16<0><<<dim3(4, 64), blk, 0, stream>>>(xb, KPIN, pinT, proj_in_b, h, nullptr, DIMM);

    for (int l = 0; l < NDEPTH; ++l) {
        const u16* wqkv = qkvT + (size_t)l * 1536 * DIMM;
        const u16* wo = woT + (size_t)l * DIMM * DIMM;
        const u16* w1 = w1T + (size_t)l * HID * DIMM;
        const u16* w2 = w2T + (size_t)l * DIMM * HID;

        scalenorm_kernel<<<TOKENS, blk, 0, stream>>>(h, ab, g_attn + l);
        gemm_bf16<7><<<dim3(12, 64), blk, 0, stream>>>(ab, DIMM, wqkv, nullptr, nullptr, qb, DIMM);
        fattn_kernel<<<dim3(SEQ / 64, NHEADS, BATCH), blk, 0, stream>>>(qb, kb, vb, relpos, ob);
        gemm_bf16<2><<<dim3(4, 64), blk, 0, stream>>>(ob, DIMM, wo, bo + (size_t)l * DIMM, h, nullptr, DIMM);
        scalenorm_kernel<<<TOKENS, blk, 0, stream>>>(h, ab, g_ff + l);
        gemm_bf16<3><<<dim3(16, 64), blk, 0, stream>>>(ab, DIMM, w1, b1 + (size_t)l * HID, nullptr, ff, HID);
        gemm_bf16<2><<<dim3(4, 64), blk, 0, stream>>>(ff, HID, w2, b2 + (size_t)l * DIMM, h, nullptr, DIMM);
    }

    ln_kernel<<<TOKENS, blk, 0, stream>>>(h, ab, ln_g, ln_b);
    gemm_bf16<4><<<dim3(5, 64), blk, 0, stream>>>(ab, DIMM, poutT, proj_out_b, out, ci, 524);
    gemm_bf16<5><<<dim3(8, 64), blk, 0, stream>>>(ci, DIMM, clsT, cls_b, out, nullptr, NCLS_);
}

// Round 5
// 1696.071 us; speedup vs baseline: 14.7450x; 1.1253x over previous
//
#include <hip/hip_runtime.h>
#include <math.h>

#define TOKENS 8192
#define SEQ    1024
#define BATCH  8
#define DIMM   512
#define NHEADS 8
#define DH     64
#define NDEPTH 6
#define HID    2048
#define NCLS_  1024
#define OUTC   1036   // NCLS + 12
#define KPIN   544    // DIN=524 padded to multiple of 32

typedef __attribute__((ext_vector_type(8))) short bf16x8;
typedef __attribute__((ext_vector_type(4))) float f32x4;

__device__ __forceinline__ float b2f(unsigned short u) {
    return __uint_as_float(((unsigned)u) << 16);
}
__device__ __forceinline__ unsigned short f2b(float f) {
    unsigned u = __float_as_uint(f);
    u += 0x7FFFu + ((u >> 16) & 1u);
    return (unsigned short)(u >> 16);
}
__device__ __forceinline__ void gl_lds16(const void* g, void* l) {
    __builtin_amdgcn_global_load_lds((const __attribute__((address_space(1))) void*)g,
                                     (__attribute__((address_space(3))) void*)l, 16, 0, 0);
}

// ---------------------------------------------------------------------------
// bf16 MFMA GEMM (m97 structure): C = A[M,Kp] @ Bt[N,Kp]^T, 128x128 tile,
// BK=32, 4 waves (2x2), 4x4 16x16x32 fragments per wave.
// MODE: 0 bias->fp32 | 1 plain->bf16 | 2 bias+residual->fp32 (Cf += )
//       3 bias+gelu->bf16 | 4 proj_out (bf16 clsin + passthrough scatter)
//       5 cls transpose scatter -> fp32 | 7 fused QKV epilogue
//       (RoPE on Q,K; V written transposed [b,h,d,s])
// ---------------------------------------------------------------------------
template<int MODE>
__global__ __launch_bounds__(256) void gemm_bf16(
    const unsigned short* __restrict__ A, int Kp,
    const unsigned short* __restrict__ Bt,
    const float* __restrict__ bias,
    float* __restrict__ Cf,
    unsigned short* __restrict__ Cb,
    int N)
{
    __shared__ unsigned short As[128 * 32];
    __shared__ unsigned short Bs[128 * 32];
    const int tid = threadIdx.x;
    const int lane = tid & 63, wid = tid >> 6;
    const int wr = wid >> 1, wc = wid & 1;
    const int m0 = blockIdx.y * 128, n0 = blockIdx.x * 128;

    f32x4 acc[4][4] = {};

    const int srow = lane >> 2;          // row within 16-row chunk
    const int skk  = (lane & 3) * 8;     // k offset within 32

    for (int k0 = 0; k0 < Kp; k0 += 32) {
        #pragma unroll
        for (int c = 0; c < 2; ++c) {
            int chunk = wid * 2 + c;
            int row = chunk * 16 + srow;
            gl_lds16(A  + (size_t)(m0 + row) * Kp + k0 + skk, As + chunk * 512);
            gl_lds16(Bt + (size_t)(n0 + row) * Kp + k0 + skk, Bs + chunk * 512);
        }
        __syncthreads();
        bf16x8 a[4], b[4];
        const int fr = lane & 15, fo = (lane >> 4) * 8;
        #pragma unroll
        for (int mi = 0; mi < 4; ++mi)
            a[mi] = *(const bf16x8*)(As + (wr * 64 + mi * 16 + fr) * 32 + fo);
        #pragma unroll
        for (int ni = 0; ni < 4; ++ni)
            b[ni] = *(const bf16x8*)(Bs + (wc * 64 + ni * 16 + fr) * 32 + fo);
        #pragma unroll
        for (int mi = 0; mi < 4; ++mi)
            #pragma unroll
            for (int ni = 0; ni < 4; ++ni)
                acc[mi][ni] = __builtin_amdgcn_mfma_f32_16x16x32_bf16(a[mi], b[ni], acc[mi][ni], 0, 0, 0);
        __syncthreads();
    }

    const int col16 = lane & 15;
    const int rbase = (lane >> 4) * 4;

    if (MODE == 7) {
        // fused QKV: wave's 64-col block lies in one of Q(0)/K(1)/V(2)
        const int nbase = n0 + wc * 64;
        const int which = nbase >> 9;
        const int col0 = nbase & 511;
        if (which < 2) {
            unsigned short* dst = Cb + (size_t)which * ((size_t)TOKENS * DIMM);
            const float invp = powf(10000.0f, -(float)col16 * (1.0f / 16.0f));
            #pragma unroll
            for (int mi = 0; mi < 4; ++mi) {
                #pragma unroll
                for (int r = 0; r < 4; ++r) {
                    int mm = m0 + wr * 64 + mi * 16 + rbase + r;
                    int s = mm & (SEQ - 1);
                    float sn, cs;
                    sincosf((float)s * invp, &sn, &cs);
                    float v0 = acc[mi][0][r], v1 = acc[mi][1][r];
                    size_t base = (size_t)mm * DIMM + col0 + col16;
                    dst[base]      = f2b(v0 * cs - v1 * sn);
                    dst[base + 16] = f2b(v1 * cs + v0 * sn);
                    dst[base + 32] = f2b(acc[mi][2][r]);
                    dst[base + 48] = f2b(acc[mi][3][r]);
                }
            }
        } else {
            // V transposed: vt[(b*8+h)*64 + dh][s], 4 consecutive s per lane
            unsigned short* vtb = Cb + (size_t)2 * TOKENS * DIMM;
            #pragma unroll
            for (int mi = 0; mi < 4; ++mi) {
                int mm = m0 + wr * 64 + mi * 16 + rbase;
                int bb = mm >> 10, ss = mm & 1023;
                #pragma unroll
                for (int ni = 0; ni < 4; ++ni) {
                    int d_full = col0 + ni * 16 + col16;
                    unsigned short t4[4];
                    #pragma unroll
                    for (int r = 0; r < 4; ++r) t4[r] = f2b(acc[mi][ni][r]);
                    size_t idx = ((size_t)(bb * NHEADS + (d_full >> 6)) * DH + (d_full & 63)) * SEQ + ss;
                    *(uint2*)(vtb + idx) = *(uint2*)t4;
                }
            }
        }
        return;
    }

    #pragma unroll
    for (int mi = 0; mi < 4; ++mi) {
        #pragma unroll
        for (int ni = 0; ni < 4; ++ni) {
            int nn = n0 + wc * 64 + ni * 16 + col16;
            if (MODE == 4 && nn >= 524) continue;
            float bv = (MODE == 1) ? 0.f : bias[nn];
            #pragma unroll
            for (int r = 0; r < 4; ++r) {
                int mm = m0 + wr * 64 + mi * 16 + rbase + r;
                float vv = acc[mi][ni][r] + bv;
                if (MODE == 3) vv = 0.5f * vv * (1.0f + erff(vv * 0.70710678118654752f));
                if (MODE == 0) Cf[(size_t)mm * N + nn] = vv;
                if (MODE == 1 || MODE == 3) Cb[(size_t)mm * N + nn] = f2b(vv);
                if (MODE == 2) Cf[(size_t)mm * N + nn] += vv;
                if (MODE == 4) {
                    if (nn < 512) Cb[(size_t)mm * 512 + nn] = f2b(vv);
                    else {
                        int bb = mm >> 10, ss = mm & 1023;
                        Cf[(size_t)bb * (SEQ * OUTC) + (size_t)ss * OUTC + 512 + nn] = vv;
                    }
                }
                if (MODE == 5) {
                    int bb = mm >> 10, ss = mm & 1023;
                    Cf[(size_t)bb * (NCLS_ * OUTC) + (size_t)nn * OUTC + ss] = vv;
                }
            }
        }
    }
}

// ---------------------------------------------------------------------------
// Weight convert: fp32 src[K][N] -> bf16 dst[Np][Kp] (transposed, zero-padded)
// ---------------------------------------------------------------------------
__global__ __launch_bounds__(256) void convw_kernel(
    const float* __restrict__ src, unsigned short* __restrict__ dst,
    int K, int N, int Kp, long sstride, long dstride)
{
    src += (size_t)blockIdx.z * sstride;
    dst += (size_t)blockIdx.z * dstride;
    __shared__ float t[32][33];
    int k0 = blockIdx.y * 32, n0 = blockIdx.x * 32;
    int tx = threadIdx.x & 31, ty = threadIdx.x >> 5;
    #pragma unroll
    for (int i = 0; i < 4; ++i) {
        int k = k0 + ty + i * 8, n = n0 + tx;
        t[ty + i * 8][tx] = (k < K && n < N) ? src[(size_t)k * N + n] : 0.f;
    }
    __syncthreads();
    #pragma unroll
    for (int i = 0; i < 4; ++i) {
        int n = n0 + ty + i * 8;
        dst[(size_t)n * Kp + k0 + tx] = f2b(t[tx][ty + i * 8]);
    }
}

// ---------------------------------------------------------------------------
// Embedding + feature concat -> bf16 [TOKENS][KPIN]
// ---------------------------------------------------------------------------
__global__ __launch_bounds__(256) void embed_kernel(
    const float* __restrict__ saml, const float* __restrict__ emb,
    unsigned short* __restrict__ x)
{
    int e = blockIdx.x * 256 + threadIdx.x;
    if (e >= TOKENS * KPIN) return;
    int t = e / KPIN, c = e % KPIN;
    int b = t >> 10, s = t & 1023;
    const float* row = saml + ((size_t)b * 1025 + s) * 13;
    float v;
    if (c < DIMM) v = emb[(size_t)((int)row[0]) * DIMM + c];
    else if (c < 524) v = row[1 + (c - DIMM)];
    else v = 0.f;
    x[(size_t)t * KPIN + c] = f2b(v);
}

// ---------------------------------------------------------------------------
// ScaleNorm: wave per row, no LDS/barriers. fp32 in -> bf16 out
// ---------------------------------------------------------------------------
__global__ __launch_bounds__(256) void scalenorm_kernel(
    const float* __restrict__ x, unsigned short* __restrict__ y,
    const float* __restrict__ gptr)
{
    int row = blockIdx.x * 4 + (threadIdx.x >> 6);
    int lane = threadIdx.x & 63;
    const float* xr = x + (size_t)row * DIMM + lane * 8;
    float4 a = *(const float4*)xr;
    float4 c = *(const float4*)(xr + 4);
    float ss = a.x*a.x + a.y*a.y + a.z*a.z + a.w*a.w
             + c.x*c.x + c.y*c.y + c.z*c.z + c.w*c.w;
    #pragma unroll
    for (int off = 1; off < 64; off <<= 1) ss += __shfl_xor(ss, off, 64);
    float n = sqrtf(ss) * 0.04419417382415922f;
    float f = gptr[0] / fmaxf(n, 1e-5f);
    unsigned short t8[8] = { f2b(a.x*f), f2b(a.y*f), f2b(a.z*f), f2b(a.w*f),
                             f2b(c.x*f), f2b(c.y*f), f2b(c.z*f), f2b(c.w*f) };
    *(uint4*)(y + (size_t)row * DIMM + lane * 8) = *(uint4*)t8;
}

// ---------------------------------------------------------------------------
// LayerNorm: wave per row. fp32 in -> bf16 out
// ---------------------------------------------------------------------------
__global__ __launch_bounds__(256) void ln_kernel(
    const float* __restrict__ x, unsigned short* __restrict__ y,
    const float* __restrict__ g, const float* __restrict__ bb)
{
    int row = blockIdx.x * 4 + (threadIdx.x >> 6);
    int lane = threadIdx.x & 63;
    const float* xr = x + (size_t)row * DIMM + lane * 8;
    float v[8];
    *(float4*)&v[0] = *(const float4*)xr;
    *(float4*)&v[4] = *(const float4*)(xr + 4);
    float sum = 0.f;
    #pragma unroll
    for (int j = 0; j < 8; ++j) sum += v[j];
    #pragma unroll
    for (int off = 1; off < 64; off <<= 1) sum += __shfl_xor(sum, off, 64);
    float mu = sum * (1.0f / 512.0f);
    float vs = 0.f;
    #pragma unroll
    for (int j = 0; j < 8; ++j) { v[j] -= mu; vs += v[j] * v[j]; }
    #pragma unroll
    for (int off = 1; off < 64; off <<= 1) vs += __shfl_xor(vs, off, 64);
    float inv = 1.0f / sqrtf(vs * (1.0f / 512.0f) + 1e-5f);
    float4 g0 = *(const float4*)(g + lane * 8), g1 = *(const float4*)(g + lane * 8 + 4);
    float4 b0 = *(const float4*)(bb + lane * 8), b1 = *(const float4*)(bb + lane * 8 + 4);
    float gg[8] = {g0.x,g0.y,g0.z,g0.w,g1.x,g1.y,g1.z,g1.w};
    float bv[8] = {b0.x,b0.y,b0.z,b0.w,b1.x,b1.y,b1.z,b1.w};
    unsigned short t8[8];
    #pragma unroll
    for (int j = 0; j < 8; ++j) t8[j] = f2b(v[j] * inv * gg[j] + bv[j]);
    *(uint4*)(y + (size_t)row * DIMM + lane * 8) = *(uint4*)t8;
}

// ---------------------------------------------------------------------------
// MFMA flash attention v2. Grid (8, NHEADS, BATCH); 4 waves x 32-row strips
// (QBLK=128). K and V^T staged as [64][64] u16 with 16B-chunk XOR swizzle
// (chunk' = chunk ^ (row&7)), loaded via global_load_lds with pre-swizzled
// source addresses. P staged bf16 [128][64], same swizzle. blockIdx.x is
// remapped so consecutive blocks pair (qt, 7-qt) for uniform work.
// ---------------------------------------------------------------------------
__global__ __launch_bounds__(256) void fattn_kernel(
    const unsigned short* __restrict__ q, const unsigned short* __restrict__ k,
    const unsigned short* __restrict__ vt,
    const float* __restrict__ relpos, unsigned short* __restrict__ o)
{
    const int bx = blockIdx.x;
    const int qt = (bx & 1) ? (7 - (bx >> 1)) : (bx >> 1);
    const int h = blockIdx.y, b = blockIdx.z;
    const int tid = threadIdx.x;
    const int lane = tid & 63, wid = tid >> 6;
    const int l15 = lane & 15, hi = lane >> 4;

    __shared__ __align__(16) unsigned short Ks[64 * 64];
    __shared__ __align__(16) unsigned short Vs[64 * 64];
    __shared__ __align__(16) unsigned short Ps[128 * 64];
    __shared__ float bias_d[SEQ];

    const size_t bh = (size_t)b * SEQ * DIMM + (size_t)h * DH;
    const unsigned short* vtg = vt + (size_t)(b * NHEADS + h) * DH * SEQ;
    const int i0 = qt * 128;

    for (int n = tid; n < SEQ; n += 256) {
        int bucket;
        if (n < 4) bucket = n;
        else {
            int vl = 4 + (int)(logf((float)n * 0.25f) * (4.0f / logf(8.0f)));
            bucket = vl < 7 ? vl : 7;
        }
        bias_d[n] = relpos[bucket * NHEADS + h] * 8.0f;
    }

    // Q fragments in registers: wave strip rows i0 + wid*32 + mi*16 + l15
    bf16x8 qf[2][2];
    #pragma unroll
    for (int mi = 0; mi < 2; ++mi) {
        const unsigned short* qrow = q + bh + (size_t)(i0 + wid * 32 + mi * 16 + l15) * DIMM;
        qf[mi][0] = *(const bf16x8*)(qrow + hi * 8);
        qf[mi][1] = *(const bf16x8*)(qrow + 32 + hi * 8);
    }

    f32x4 o_acc[2][4] = {};
    float m_r[2][4], l_r[2][4];
    #pragma unroll
    for (int mi = 0; mi < 2; ++mi)
        #pragma unroll
        for (int r = 0; r < 4; ++r) { m_r[mi][r] = -3.0e38f; l_r[mi][r] = 0.f; }

    const int s_lo = i0 + wid * 32;
    const int jtmax = 2 * qt + 1;

    // swizzled chunk index for fragment reads: (4*kk+hi) ^ (l15&7)
    const int swz = l15 & 7;

    for (int jt = 0; jt <= jtmax; ++jt) {
        const int j0 = jt * 64;
        __syncthreads();      // previous tile fully consumed
        #pragma unroll
        for (int it = 0; it < 2; ++it) {
            int ci = (wid * 2 + it) * 64 + lane;   // chunk index 0..511
            int j = ci >> 3, cp = ci & 7;
            int cs = cp ^ (j & 7);                 // inverse-swizzled source chunk
            gl_lds16(k + bh + (size_t)(j0 + j) * DIMM + cs * 8,
                     Ks + (size_t)(wid * 2 + it) * 512);
            gl_lds16(vtg + (size_t)j * SEQ + j0 + cs * 8,
                     Vs + (size_t)(wid * 2 + it) * 512);
        }
        __syncthreads();

        if (j0 <= s_lo + 31) {
            // S = Q K^T
            f32x4 sacc[2][4] = {};
            #pragma unroll
            for (int nj = 0; nj < 4; ++nj) {
                int row = nj * 16 + l15;
                #pragma unroll
                for (int kk = 0; kk < 2; ++kk) {
                    bf16x8 kf = *(const bf16x8*)(Ks + row * 64 + (((4 * kk + hi) ^ swz) << 3));
                    sacc[0][nj] = __builtin_amdgcn_mfma_f32_16x16x32_bf16(qf[0][kk], kf, sacc[0][nj], 0, 0, 0);
                    sacc[1][nj] = __builtin_amdgcn_mfma_f32_16x16x32_bf16(qf[1][kk], kf, sacc[1][nj], 0, 0, 0);
                }
            }

            const bool full = (j0 + 63 <= s_lo);
            #pragma unroll
            for (int mi = 0; mi < 2; ++mi) {
                float s4[4][4];
                #pragma unroll
                for (int nj = 0; nj < 4; ++nj) {
                    int gj = j0 + nj * 16 + l15;
                    #pragma unroll
                    for (int r = 0; r < 4; ++r) {
                        int gi = s_lo + mi * 16 + hi * 4 + r;
                        int d = gi - gj;
                        float bd = bias_d[d < 0 ? 0 : d];
                        float sv = sacc[mi][nj][r] * 0.125f + bd;
                        s4[nj][r] = (!full && gj > gi) ? -3.0e38f : sv;
                    }
                }
                float rm[4];
                #pragma unroll
                for (int r = 0; r < 4; ++r)
                    rm[r] = fmaxf(fmaxf(s4[0][r], s4[1][r]), fmaxf(s4[2][r], s4[3][r]));
                #pragma unroll
                for (int off = 1; off < 16; off <<= 1)
                    #pragma unroll
                    for (int r = 0; r < 4; ++r)
                        rm[r] = fmaxf(rm[r], __shfl_xor(rm[r], off, 64));
                float pscale[4], rs[4] = {};
                #pragma unroll
                for (int r = 0; r < 4; ++r) {
                    float mn = fmaxf(m_r[mi][r], rm[r]);
                    pscale[r] = __expf(m_r[mi][r] - mn);
                    m_r[mi][r] = mn;
                }
                #pragma unroll
                for (int nj = 0; nj < 4; ++nj) {
                    int chunk = 2 * nj + (l15 >> 3);
                    #pragma unroll
                    for (int r = 0; r < 4; ++r) {
                        float e = __expf(s4[nj][r] - m_r[mi][r]);
                        rs[r] += e;
                        int i_loc = wid * 32 + mi * 16 + hi * 4 + r;
                        Ps[i_loc * 64 + ((chunk ^ (i_loc & 7)) << 3) + (l15 & 7)] = f2b(e);
                    }
                }
                #pragma unroll
                for (int off = 1; off < 16; off <<= 1)
                    #pragma unroll
                    for (int r = 0; r < 4; ++r)
                        rs[r] += __shfl_xor(rs[r], off, 64);
                #pragma unroll
                for (int r = 0; r < 4; ++r)
                    l_r[mi][r] = l_r[mi][r] * pscale[r] + rs[r];
                #pragma unroll
                for (int ni = 0; ni < 4; ++ni)
                    #pragma unroll
                    for (int r = 0; r < 4; ++r)
                        o_acc[mi][ni][r] *= pscale[r];
            }

            // O += P V  (Ps rows are wave-private; compiler orders LDS ops)
            #pragma unroll
            for (int kk = 0; kk < 2; ++kk) {
                int rp0 = wid * 32 + l15;
                int rp1 = wid * 32 + 16 + l15;
                bf16x8 pf0 = *(const bf16x8*)(Ps + rp0 * 64 + (((4 * kk + hi) ^ (rp0 & 7)) << 3));
                bf16x8 pf1 = *(const bf16x8*)(Ps + rp1 * 64 + (((4 * kk + hi) ^ (rp1 & 7)) << 3));
                #pragma unroll
                for (int ni = 0; ni < 4; ++ni) {
                    int rv = ni * 16 + l15;
                    bf16x8 vf = *(const bf16x8*)(Vs + rv * 64 + (((4 * kk + hi) ^ swz) << 3));
                    o_acc[0][ni] = __builtin_amdgcn_mfma_f32_16x16x32_bf16(pf0, vf, o_acc[0][ni], 0, 0, 0);
                    o_acc[1][ni] = __builtin_amdgcn_mfma_f32_16x16x32_bf16(pf1, vf, o_acc[1][ni], 0, 0, 0);
                }
            }
        }
    }

    #pragma unroll
    for (int mi = 0; mi < 2; ++mi)
        #pragma unroll
        for (int r = 0; r < 4; ++r) {
            float inv = 1.0f / l_r[mi][r];
            int gi = i0 + wid * 32 + mi * 16 + hi * 4 + r;
            #pragma unroll
            for (int ni = 0; ni < 4; ++ni)
                o[bh + (size_t)gi * DIMM + ni * 16 + l15] = f2b(o_acc[mi][ni][r] * inv);
        }
}

// ---------------------------------------------------------------------------
extern "C" void kernel_launch(void* const* d_in, const int* in_sizes, int n_in,
                              void* d_out, int out_size, void* d_ws, size_t ws_size,
                              hipStream_t stream)
{
    const float* saml       = (const float*)d_in[0];
    const float* emb_table  = (const float*)d_in[1];
    const float* proj_in_w  = (const float*)d_in[2];
    const float* proj_in_b  = (const float*)d_in[3];
    const float* g_attn     = (const float*)d_in[4];
    const float* g_ff       = (const float*)d_in[5];
    const float* Wq         = (const float*)d_in[6];
    const float* Wk         = (const float*)d_in[7];
    const float* Wv         = (const float*)d_in[8];
    const float* Wo         = (const float*)d_in[9];
    const float* bo         = (const float*)d_in[10];
    const float* relpos     = (const float*)d_in[11];
    const float* W1         = (const float*)d_in[12];
    const float* b1         = (const float*)d_in[13];
    const float* W2         = (const float*)d_in[14];
    const float* b2         = (const float*)d_in[15];
    const float* ln_g       = (const float*)d_in[16];
    const float* ln_b       = (const float*)d_in[17];
    const float* proj_out_w = (const float*)d_in[18];
    const float* proj_out_b = (const float*)d_in[19];
    const float* cls_w      = (const float*)d_in[20];
    const float* cls_b      = (const float*)d_in[21];
    float* out = (float*)d_out;

    char* wsp = (char*)d_ws;
    size_t woff = 0;
    auto carve = [&](size_t bytes) -> char* {
        char* p = wsp + woff;
        woff += (bytes + 255) & ~(size_t)255;
        return p;
    };
    typedef unsigned short u16;
    float* h  = (float*)carve((size_t)TOKENS * DIMM * 4);
    u16* qb   = (u16*)carve((size_t)TOKENS * DIMM * 2 * 3); // q, k, vt contiguous
    u16* kb   = qb + (size_t)TOKENS * DIMM;
    u16* vtb  = kb + (size_t)TOKENS * DIMM;                 // [b][h][d][s]
    u16* ab   = (u16*)carve((size_t)TOKENS * DIMM * 2);     // norm outputs
    u16* ob   = (u16*)carve((size_t)TOKENS * DIMM * 2);     // attention out
    u16* ff   = (u16*)carve((size_t)TOKENS * HID * 2);
    u16* ci   = (u16*)carve((size_t)TOKENS * DIMM * 2);     // cls input
    u16* xb   = (u16*)carve((size_t)TOKENS * KPIN * 2);
    u16* qkvT = (u16*)carve((size_t)NDEPTH * 1536 * DIMM * 2);
    u16* woT  = (u16*)carve((size_t)NDEPTH * DIMM * DIMM * 2);
    u16* w1T  = (u16*)carve((size_t)NDEPTH * HID * DIMM * 2);
    u16* w2T  = (u16*)carve((size_t)NDEPTH * DIMM * HID * 2);
    u16* pinT = (u16*)carve((size_t)DIMM * KPIN * 2);
    u16* poutT= (u16*)carve((size_t)640 * DIMM * 2);
    u16* clsT = (u16*)carve((size_t)NCLS_ * DIMM * 2);

    dim3 blk(256);

    convw_kernel<<<dim3(16, 16, 6), blk, 0, stream>>>(Wq, qkvT,             512, 512, 512, 512*512, 1536*512);
    convw_kernel<<<dim3(16, 16, 6), blk, 0, stream>>>(Wk, qkvT + 512*512,   512, 512, 512, 512*512, 1536*512);
    convw_kernel<<<dim3(16, 16, 6), blk, 0, stream>>>(Wv, qkvT + 1024*512,  512, 512, 512, 512*512, 1536*512);
    convw_kernel<<<dim3(16, 16, 6), blk, 0, stream>>>(Wo, woT, 512, 512, 512, 512*512, 512*512);
    convw_kernel<<<dim3(64, 16, 6), blk, 0, stream>>>(W1, w1T, 512, 2048, 512, 512*2048, 2048*512);
    convw_kernel<<<dim3(16, 64, 6), blk, 0, stream>>>(W2, w2T, 2048, 512, 2048, 2048*512, 512*2048);
    convw_kernel<<<dim3(16, 17, 1), blk, 0, stream>>>(proj_in_w, pinT, 524, 512, KPIN, 0, 0);
    convw_kernel<<<dim3(20, 16, 1), blk, 0, stream>>>(proj_out_w, poutT, 512, 524, 512, 0, 0);
    convw_kernel<<<dim3(32, 16, 1), blk, 0, stream>>>(cls_w, clsT, 512, 1024, 512, 0, 0);

    embed_kernel<<<(TOKENS * KPIN + 255) / 256, blk, 0, stream>>>(saml, emb_table, xb);
    gemm_bf16<0><<<dim3(4, 64), blk, 0, stream>>>(xb, KPIN, pinT, proj_in_b, h, nullptr, DIMM);

    for (int l = 0; l < NDEPTH; ++l) {
        const u16* wqkv = qkvT + (size_t)l * 1536 * DIMM;
        const u16* wo = woT + (size_t)l * DIMM * DIMM;
        const u16* w1 = w1T + (size_t)l * HID * DIMM;
        const u16* w2 = w2T + (size_t)l * DIMM * HID;

        scalenorm_kernel<<<TOKENS / 4, blk, 0, stream>>>(h, ab, g_attn + l);
        gemm_bf16<7><<<dim3(12, 64), blk, 0, stream>>>(ab, DIMM, wqkv, nullptr, nullptr, qb, DIMM);
        fattn_kernel<<<dim3(8, NHEADS, BATCH), blk, 0, stream>>>(qb, kb, vtb, relpos, ob);
        gemm_bf16<2><<<dim3(4, 64), blk, 0, stream>>>(ob, DIMM, wo, bo + (size_t)l * DIMM, h, nullptr, DIMM);
        scalenorm_kernel<<<TOKENS / 4, blk, 0, stream>>>(h, ab, g_ff + l);
        gemm_bf16<3><<<dim3(16, 64), blk, 0, stream>>>(ab, DIMM, w1, b1 + (size_t)l * HID, nullptr, ff, HID);
        gemm_bf16<2><<<dim3(4, 64), blk, 0, stream>>>(ff, HID, w2, b2 + (size_t)l * DIMM, h, nullptr, DIMM);
    }

    ln_kernel<<<TOKENS / 4, blk, 0, stream>>>(h, ab, ln_g, ln_b);
    gemm_bf16<4><<<dim3(5, 64), blk, 0, stream>>>(ab, DIMM, poutT, proj_out_b, out, ci, 524);
    gemm_bf16<5><<<dim3(8, 64), blk, 0, stream>>>(ci, DIMM, clsT, cls_b, out, nullptr, NCLS_);
}